// Round 18
// baseline (454.871 us; speedup 1.0000x reference)
//
#include <hip/hip_runtime.h>
#include <stdint.h>

#define NDATA 131072
#define NHID  32768
#define NEDGE 524288

typedef __bf16 bf16_t;
typedef __bf16 bf16x4 __attribute__((ext_vector_type(4)));
typedef __bf16 bf16x8 __attribute__((ext_vector_type(8)));
typedef float  f32x4  __attribute__((ext_vector_type(4)));

__device__ __forceinline__ float gelu_f(float x) {
    return 0.5f * x * (1.0f + erff(x * 0.7071067811865476f));
}

// direct global->LDS 16B copy: dest = lds_base + lane*16 (HW contract)
__device__ __forceinline__ void glds16(const void* g, void* l) {
    auto* gp = reinterpret_cast<const __attribute__((address_space(1))) uint32_t*>(
        reinterpret_cast<uintptr_t>(g));
    auto* lp = reinterpret_cast<__attribute__((address_space(3))) uint32_t*>(
        reinterpret_cast<uintptr_t>(l));
    __builtin_amdgcn_global_load_lds(gp, lp, 16, 0, 0);
}

struct WPtrs { const float* p[10]; };

// ---------------- batched CSR build (3 graphs), two-level sort ----------------
struct EdgePtrs { const int* src[3]; const int* dst[3]; };

__device__ __forceinline__ int cnt_off_of(int g) { return g == 0 ? 0 : (g == 1 ? NHID : 2 * NHID); }
__device__ __forceinline__ int rp_off_of(int g)  { return g == 0 ? 0 : (g == 1 ? NHID + 1 : 2 * NHID + 2); }
__device__ __forceinline__ int shift_of(int g)   { return g == 2 ? 10 : 8; }   // 128 bins

__global__ __launch_bounds__(256)
void hist3(EdgePtrs ep, int* __restrict__ cnt_all) {
    const int g = blockIdx.x >> 11;
    const int i = ((blockIdx.x & 2047) << 8) + threadIdx.x;
    atomicAdd(&cnt_all[cnt_off_of(g) + ep.dst[g][i]], 1);
}

__global__ __launch_bounds__(256)
void scan_blk3(const int* __restrict__ cnt_all, int* __restrict__ pre_all,
               int* __restrict__ blk) {
    __shared__ int sh[256];
    const int bid = blockIdx.x;
    int g, local;
    if (bid < 32)      { g = 0; local = bid; }
    else if (bid < 64) { g = 1; local = bid - 32; }
    else               { g = 2; local = bid - 64; }
    const int t = threadIdx.x;
    const int cbase = cnt_off_of(g) + local * 1024 + t * 4;
    const int pbase = rp_off_of(g)  + local * 1024 + t * 4;
    int4 v = *(const int4*)(cnt_all + cbase);
    sh[t] = v.x + v.y + v.z + v.w;
    __syncthreads();
    for (int off = 1; off < 256; off <<= 1) {
        int other = 0;
        if (t >= off) other = sh[t - off];
        __syncthreads();
        if (t >= off) sh[t] += other;
        __syncthreads();
    }
    const int excl = (t == 0) ? 0 : sh[t - 1];
    int4 o;
    o.x = excl; o.y = o.x + v.x; o.z = o.y + v.y; o.w = o.z + v.z;
    *(int4*)(pre_all + pbase) = o;
    if (t == 255) blk[bid] = sh[255];
}

__global__ __launch_bounds__(256)
void scan_add3(const int* __restrict__ pre_all, const int* __restrict__ blk,
               int* __restrict__ rp_all, int* __restrict__ binA) {
    __shared__ int sh[256];
    const int bid = blockIdx.x;
    int g, local, gbase;
    if (bid < 32)      { g = 0; local = bid;      gbase = 0; }
    else if (bid < 64) { g = 1; local = bid - 32; gbase = 32; }
    else               { g = 2; local = bid - 64; gbase = 64; }
    const int t = threadIdx.x;
    int part = 0;
    if (t < local) part = blk[gbase + t];
    sh[t] = part;
    __syncthreads();
    for (int o2 = 128; o2 > 0; o2 >>= 1) {
        if (t < o2) sh[t] += sh[t + o2];
        __syncthreads();
    }
    const int off = sh[0];
    const int idx = local * 1024 + t * 4;
    const int pbase = rp_off_of(g) + idx;
    int4 v = *(const int4*)(pre_all + pbase);
    v.x += off; v.y += off; v.z += off; v.w += off;
    *(int4*)(rp_all + pbase) = v;
    const int bw = 1 << shift_of(g);
    if ((idx & (bw - 1)) == 0) binA[g * 128 + (idx >> shift_of(g))] = v.x;
    if (local == 0 && t == 0) {
        const int n = (g == 2) ? NDATA : NHID;
        rp_all[rp_off_of(g) + n] = NEDGE;
    }
}

__global__ __launch_bounds__(256)
void partition3(EdgePtrs ep, int* __restrict__ binA, int2* __restrict__ pairs) {
    __shared__ int hist[128], base[128], cur[128];
    const int g = blockIdx.x >> 7;
    const int blk = blockIdx.x & 127;
    const int t = threadIdx.x;
    const int shift = shift_of(g);
    const int e_base = blk * 4096;
    const int* src = ep.src[g];
    const int* dst = ep.dst[g];
    if (t < 128) { hist[t] = 0; cur[t] = 0; }
    __syncthreads();
    #pragma unroll
    for (int it = 0; it < 16; ++it) {
        const int d = dst[e_base + it * 256 + t];
        atomicAdd(&hist[d >> shift], 1);
    }
    __syncthreads();
    if (t < 128) base[t] = atomicAdd(&binA[g * 128 + t], hist[t]);
    __syncthreads();
    #pragma unroll
    for (int it = 0; it < 16; ++it) {
        const int e = e_base + it * 256 + t;
        const int s = src[e], d = dst[e];
        const int b = d >> shift;
        const int l = atomicAdd(&cur[b], 1);
        pairs[(size_t)g * NEDGE + base[b] + l] = make_int2(s, d);
    }
}

__global__ __launch_bounds__(256)
void binsort3(const int2* __restrict__ pairs, const int* __restrict__ rp_all,
              int* __restrict__ sorted_all) {
    __shared__ int cur[1024];
    const int g = blockIdx.x >> 7;
    const int b = blockIdx.x & 127;
    const int t = threadIdx.x;
    const int shift = shift_of(g);
    const int W = 1 << shift;
    const int d0 = b << shift;
    const int rpo = rp_off_of(g);
    for (int i = t; i < W; i += 256) cur[i] = rp_all[rpo + d0 + i];
    __syncthreads();
    const int e0 = rp_all[rpo + d0];
    const int e1 = rp_all[rpo + d0 + W];
    for (int e = e0 + t; e < e1; e += 256) {
        const int2 p = pairs[(size_t)g * NEDGE + e];
        const int pos = atomicAdd(&cur[p.y - d0], 1);
        sorted_all[(size_t)g * NEDGE + pos] = p.x;
    }
}

// ---------------- CSR aggregation (mean), bf16 features; 4 loads in flight per half ----------------
__global__ __launch_bounds__(256)
void csr_gather_mean(const bf16_t* __restrict__ feat, const int* __restrict__ row_ptr,
                     const int* __restrict__ sorted_src, bf16_t* __restrict__ mean, int n) {
    const int lane = threadIdx.x & 63;
    const int half = lane >> 5;
    const int col8 = (lane & 31) * 8;
    const int w = blockIdx.x * 4 + (threadIdx.x >> 6);
    if (w >= n) return;
    const int e0 = row_ptr[w], e1 = row_ptr[w + 1];
    float acc[8] = {0.f, 0.f, 0.f, 0.f, 0.f, 0.f, 0.f, 0.f};
    int e = e0 + half;
    for (; e + 6 < e1; e += 8) {
        const int s0 = sorted_src[e],     s1 = sorted_src[e + 2];
        const int s2 = sorted_src[e + 4], s3 = sorted_src[e + 6];
        const bf16x8 v0 = *(const bf16x8*)(feat + (size_t)s0 * 256 + col8);
        const bf16x8 v1 = *(const bf16x8*)(feat + (size_t)s1 * 256 + col8);
        const bf16x8 v2 = *(const bf16x8*)(feat + (size_t)s2 * 256 + col8);
        const bf16x8 v3 = *(const bf16x8*)(feat + (size_t)s3 * 256 + col8);
        #pragma unroll
        for (int j = 0; j < 8; ++j)
            acc[j] += ((float)v0[j] + (float)v1[j]) + ((float)v2[j] + (float)v3[j]);
    }
    for (; e < e1; e += 2) {
        const int s0 = sorted_src[e];
        const bf16x8 v0 = *(const bf16x8*)(feat + (size_t)s0 * 256 + col8);
        #pragma unroll
        for (int j = 0; j < 8; ++j) acc[j] += (float)v0[j];
    }
    #pragma unroll
    for (int j = 0; j < 8; ++j) acc[j] += __shfl_xor(acc[j], 32, 64);
    if (half == 0) {
        const float ic = 1.0f / fmaxf((float)(e1 - e0), 1.0f);
        bf16x8 r;
        #pragma unroll
        for (int j = 0; j < 8; ++j) r[j] = (bf16_t)(acc[j] * ic);
        *(bf16x8*)(mean + (size_t)w * 256 + col8) = r;
    }
}

// ---------------- merged cvt + small-K encoders ----------------
// blocks [0,2064): weight cvt; [2064,2576): K3/NHID; [2576,4624): K8/NDATA
__global__ __launch_bounds__(256)
void enc_cvt_both(WPtrs wp, bf16_t* __restrict__ wout,
                  const float* __restrict__ hx, const float* __restrict__ w3,
                  const float* __restrict__ b3, bf16_t* __restrict__ out3,
                  const float* __restrict__ dx, const float* __restrict__ w8,
                  const float* __restrict__ b8, bf16_t* __restrict__ out8) {
    __shared__ float ws[8 * 256];
    __shared__ float bs[256];
    const int t = threadIdx.x;
    if (blockIdx.x < 2064) {
        const int i = blockIdx.x * 256 + t;
        if (i < 8 * 65536) {
            const int wsel = i >> 16, off = i & 65535;
            wout[i] = (bf16_t)wp.p[wsel][off];
        } else if (i < 8 * 65536 + 2048) {
            wout[i] = (bf16_t)wp.p[8][i - 8 * 65536];
        } else {
            wout[i] = (bf16_t)wp.p[9][i - (8 * 65536 + 2048)];
        }
        return;
    }
    const int bid = blockIdx.x - 2064;
    const bool is8 = (bid >= 512);
    if (is8) {
        #pragma unroll
        for (int j = 0; j < 8; ++j) ws[j * 256 + t] = w8[t * 8 + j];
        bs[t] = b8[t];
    } else {
        #pragma unroll
        for (int j = 0; j < 3; ++j) ws[j * 256 + t] = w3[t * 3 + j];
        bs[t] = b3[t];
    }
    __syncthreads();
    const int lane = t & 63, wv = t >> 6;
    const int f0 = lane * 4;
    const float4 b4 = *(const float4*)(&bs[f0]);
    if (!is8) {
        for (int node = bid * 4 + wv; node < NHID; node += 512 * 4) {
            const float* xr = hx + (size_t)node * 3;
            float xv[3];
            #pragma unroll
            for (int j = 0; j < 3; ++j) xv[j] = xr[j];
            float a0 = b4.x, a1 = b4.y, a2 = b4.z, a3 = b4.w;
            #pragma unroll
            for (int j = 0; j < 3; ++j) {
                const float4 w4 = *(const float4*)(&ws[j * 256 + f0]);
                a0 += xv[j] * w4.x; a1 += xv[j] * w4.y;
                a2 += xv[j] * w4.z; a3 += xv[j] * w4.w;
            }
            bf16x4 r;
            r[0] = (bf16_t)gelu_f(a0); r[1] = (bf16_t)gelu_f(a1);
            r[2] = (bf16_t)gelu_f(a2); r[3] = (bf16_t)gelu_f(a3);
            *(bf16x4*)(out3 + (size_t)node * 256 + f0) = r;
        }
    } else {
        for (int node = (bid - 512) * 4 + wv; node < NDATA; node += 2048 * 4) {
            const float* xr = dx + (size_t)node * 8;
            float xv[8];
            #pragma unroll
            for (int j = 0; j < 8; ++j) xv[j] = xr[j];
            float a0 = b4.x, a1 = b4.y, a2 = b4.z, a3 = b4.w;
            #pragma unroll
            for (int j = 0; j < 8; ++j) {
                const float4 w4 = *(const float4*)(&ws[j * 256 + f0]);
                a0 += xv[j] * w4.x; a1 += xv[j] * w4.y;
                a2 += xv[j] * w4.z; a3 += xv[j] * w4.w;
            }
            bf16x4 r;
            r[0] = (bf16_t)gelu_f(a0); r[1] = (bf16_t)gelu_f(a1);
            r[2] = (bf16_t)gelu_f(a2); r[3] = (bf16_t)gelu_f(a3);
            *(bf16x4*)(out8 + (size_t)node * 256 + f0) = r;
        }
    }
}

// ---------------- MFMA bf16 GEMM — 64x128 tile ----------------
template<int DUAL, int ACT>
__global__ __launch_bounds__(256)
void mfma_gemm(const bf16_t* __restrict__ A1, const bf16_t* __restrict__ W1,
               const bf16_t* __restrict__ A2, const bf16_t* __restrict__ W2,
               const float* __restrict__ bias, bf16_t* __restrict__ C) {
    __shared__ bf16_t As[4 * 64 * 8];    // 4 KB
    __shared__ bf16_t Bs[4 * 128 * 8];   // 8 KB
    const int t = threadIdx.x;
    const int w = t >> 6, lane = t & 63;
    const int l15 = lane & 15, l4 = lane >> 4;
    const int m0 = (blockIdx.x >> 1) * 64;
    const int n0 = (blockIdx.x & 1) * 128;

    f32x4 acc[4][2];
    #pragma unroll
    for (int nb = 0; nb < 2; ++nb) {
        const float bv = bias ? bias[n0 + w * 32 + nb * 16 + l15] : 0.0f;
        #pragma unroll
        for (int m = 0; m < 4; ++m) {
            acc[m][nb][0] = bv; acc[m][nb][1] = bv; acc[m][nb][2] = bv; acc[m][nb][3] = bv;
        }
    }

    #pragma unroll
    for (int p = 0; p <= DUAL; ++p) {
        const bf16_t* Ap = p ? A2 : A1;
        const bf16_t* Wp = p ? W2 : W1;
        for (int kt = 0; kt < 8; ++kt) {
            const int k0 = kt * 32;
            __syncthreads();
            glds16(Ap + (size_t)(m0 + lane) * 256 + k0 + w * 8, &As[(w * 64) * 8]);
            glds16(Wp + (size_t)(n0 + lane) * 256 + k0 + w * 8, &Bs[(w * 128) * 8]);
            glds16(Wp + (size_t)(n0 + 64 + lane) * 256 + k0 + w * 8, &Bs[(w * 128 + 64) * 8]);
            __syncthreads();
            bf16x8 af[4], bfr[2];
            #pragma unroll
            for (int m = 0; m < 4; ++m)
                af[m] = *(const bf16x8*)(&As[(l4 * 64 + m * 16 + l15) * 8]);
            #pragma unroll
            for (int nb = 0; nb < 2; ++nb)
                bfr[nb] = *(const bf16x8*)(&Bs[(l4 * 128 + w * 32 + nb * 16 + l15) * 8]);
            #pragma unroll
            for (int m = 0; m < 4; ++m)
                #pragma unroll
                for (int nb = 0; nb < 2; ++nb)
                    acc[m][nb] = __builtin_amdgcn_mfma_f32_16x16x32_bf16(af[m], bfr[nb], acc[m][nb], 0, 0, 0);
        }
    }

    #pragma unroll
    for (int m = 0; m < 4; ++m) {
        #pragma unroll
        for (int nb = 0; nb < 2; ++nb) {
            const int col = n0 + w * 32 + nb * 16 + l15;
            #pragma unroll
            for (int i = 0; i < 4; ++i) {
                const int row = m0 + m * 16 + l4 * 4 + i;
                const float v = acc[m][nb][i];
                C[(size_t)row * 256 + col] = (bf16_t)(ACT ? gelu_f(v) : v);
            }
        }
    }
}

// ---------------- chained dual GEMM: C = (gelu(b1 + A1@W1^T)) @ W2^T ----------------
__global__ __launch_bounds__(256)
void gemm_chain2(const bf16_t* __restrict__ A1, const bf16_t* __restrict__ W1,
                 const float* __restrict__ b1, const bf16_t* __restrict__ W2,
                 bf16_t* __restrict__ C) {
    __shared__ bf16_t As[4 * 64 * 8];     // 4 KB
    __shared__ bf16_t Bs[4 * 256 * 8];    // 16 KB
    __shared__ bf16_t sL[32 * 64 * 8];    // 32 KB
    const int t = threadIdx.x;
    const int w = t >> 6, lane = t & 63;
    const int l15 = lane & 15, l4 = lane >> 4;
    const int m0 = blockIdx.x * 64;

    f32x4 acc[4][4];
    #pragma unroll
    for (int nb = 0; nb < 4; ++nb) {
        const float bv = b1[w * 64 + nb * 16 + l15];
        #pragma unroll
        for (int m = 0; m < 4; ++m) {
            acc[m][nb][0] = bv; acc[m][nb][1] = bv; acc[m][nb][2] = bv; acc[m][nb][3] = bv;
        }
    }

    for (int kt = 0; kt < 8; ++kt) {
        const int k0 = kt * 32;
        __syncthreads();
        glds16(A1 + (size_t)(m0 + lane) * 256 + k0 + w * 8, &As[(w * 64) * 8]);
        #pragma unroll
        for (int q = 0; q < 4; ++q)
            glds16(W1 + (size_t)(w * 64 + lane) * 256 + k0 + q * 8,
                   &Bs[(q * 256 + w * 64) * 8]);
        __syncthreads();
        bf16x8 af[4], bfr[4];
        #pragma unroll
        for (int m = 0; m < 4; ++m)
            af[m] = *(const bf16x8*)(&As[(l4 * 64 + m * 16 + l15) * 8]);
        #pragma unroll
        for (int nb = 0; nb < 4; ++nb)
            bfr[nb] = *(const bf16x8*)(&Bs[(l4 * 256 + w * 64 + nb * 16 + l15) * 8]);
        #pragma unroll
        for (int m = 0; m < 4; ++m)
            #pragma unroll
            for (int nb = 0; nb < 4; ++nb)
                acc[m][nb] = __builtin_amdgcn_mfma_f32_16x16x32_bf16(af[m], bfr[nb], acc[m][nb], 0, 0, 0);
    }
    #pragma unroll
    for (int m = 0; m < 4; ++m) {
        #pragma unroll
        for (int nb = 0; nb < 4; ++nb) {
            const int col = w * 64 + nb * 16 + l15;
            const int kq = col >> 3, cj = col & 7;
            #pragma unroll
            for (int i = 0; i < 4; ++i) {
                const int row = m * 16 + l4 * 4 + i;
                sL[(kq * 64 + row) * 8 + cj] = (bf16_t)gelu_f(acc[m][nb][i]);
            }
            acc[m][nb][0] = 0.f; acc[m][nb][1] = 0.f; acc[m][nb][2] = 0.f; acc[m][nb][3] = 0.f;
        }
    }
    __syncthreads();

    for (int kt = 0; kt < 8; ++kt) {
        const int k0 = kt * 32;
        __syncthreads();
        #pragma unroll
        for (int q = 0; q < 4; ++q)
            glds16(W2 + (size_t)(w * 64 + lane) * 256 + k0 + q * 8,
                   &Bs[(q * 256 + w * 64) * 8]);
        __syncthreads();
        bf16x8 af[4], bfr[4];
        #pragma unroll
        for (int m = 0; m < 4; ++m)
            af[m] = *(const bf16x8*)(&sL[((kt * 4 + l4) * 64 + m * 16 + l15) * 8]);
        #pragma unroll
        for (int nb = 0; nb < 4; ++nb)
            bfr[nb] = *(const bf16x8*)(&Bs[(l4 * 256 + w * 64 + nb * 16 + l15) * 8]);
        #pragma unroll
        for (int m = 0; m < 4; ++m)
            #pragma unroll
            for (int nb = 0; nb < 4; ++nb)
                acc[m][nb] = __builtin_amdgcn_mfma_f32_16x16x32_bf16(af[m], bfr[nb], acc[m][nb], 0, 0, 0);
    }

    #pragma unroll
    for (int m = 0; m < 4; ++m) {
        #pragma unroll
        for (int nb = 0; nb < 4; ++nb) {
            const int col = w * 64 + nb * 16 + l15;
            #pragma unroll
            for (int i = 0; i < 4; ++i) {
                const int row = m0 + m * 16 + l4 * 4 + i;
                C[(size_t)row * 256 + col] = (bf16_t)acc[m][nb][i];
            }
        }
    }
}

// ---------------- decoder: t = gelu(dec_bl + mean(sW) + d@W2^T), out = t@ow^T + ob ----------------
// d precomputed to dL once (1 barrier); main loop ZERO barriers: B frags direct global->VGPR,
// dL read-only. mean-add via identity-MFMA. Wd/bd read from L2-hot globals.
__global__ __launch_bounds__(256)
void dec_gemm_m(const bf16_t* __restrict__ A1mean,
                const float* __restrict__ xdat, const bf16_t* __restrict__ wdb,
                const float* __restrict__ bd, const bf16_t* __restrict__ W2,
                const float* __restrict__ bias, const bf16_t* __restrict__ owb,
                const float* __restrict__ ob, float* __restrict__ out) {
    __shared__ __align__(16) char smem[32768];
    bf16_t* dL = (bf16_t*)smem;                // 32 KB [32 kq][64 rows][8] — full d tile
    // epilogue overlays (dL dead):
    bf16_t* tt   = (bf16_t*)smem;              // 16 KB
    float*  part = (float*)(smem + 16384);     // 8 KB

    const int t = threadIdx.x;
    const int w = t >> 6, lane = t & 63;
    const int l15 = lane & 15, l4 = lane >> 4;
    const int m0 = blockIdx.x * 64;

    // x A-fragment for the K=8 d-MFMA (lanes l4>0 hold zeros)
    bf16x8 af_x;
    #pragma unroll
    for (int j = 0; j < 8; ++j) af_x[j] = (bf16_t)0.0f;
    if (l4 == 0) {
        const float* xrp = xdat + (size_t)(m0 + w * 16 + l15) * 8;
        const float4 xa = *(const float4*)(xrp);
        const float4 xb = *(const float4*)(xrp + 4);
        af_x[0] = (bf16_t)xa.x; af_x[1] = (bf16_t)xa.y; af_x[2] = (bf16_t)xa.z; af_x[3] = (bf16_t)xa.w;
        af_x[4] = (bf16_t)xb.x; af_x[5] = (bf16_t)xb.y; af_x[6] = (bf16_t)xb.z; af_x[7] = (bf16_t)xb.w;
    }

    // d-phase: wave w computes rows w*16..w*16+15, all 256 cols, into dL
    #pragma unroll
    for (int cb = 0; cb < 16; ++cb) {
        const int col = cb * 16 + l15;
        f32x4 ad;
        const float bv = bd[col];
        ad[0] = bv; ad[1] = bv; ad[2] = bv; ad[3] = bv;
        bf16x8 bf_d;
        #pragma unroll
        for (int j = 0; j < 8; ++j) bf_d[j] = (bf16_t)0.0f;
        if (l4 == 0) bf_d = *(const bf16x8*)(wdb + col * 8);
        ad = __builtin_amdgcn_mfma_f32_16x16x32_bf16(af_x, bf_d, ad, 0, 0, 0);
        const int kq = col >> 3, jj = col & 7;
        #pragma unroll
        for (int i = 0; i < 4; ++i)
            dL[(kq * 64 + w * 16 + l4 * 4 + i) * 8 + jj] = (bf16_t)gelu_f(ad[i]);
    }

    // acc init: bias + mean(sW) via identity-MFMA (overlaps d-phase latency)
    f32x4 acc[4][4];
    #pragma unroll
    for (int nb = 0; nb < 4; ++nb) {
        const float bv = bias[w * 64 + nb * 16 + l15];
        #pragma unroll
        for (int m = 0; m < 4; ++m) {
            acc[m][nb][0] = bv; acc[m][nb][1] = bv; acc[m][nb][2] = bv; acc[m][nb][3] = bv;
        }
    }
    {
        bf16x8 ifr[2];
        #pragma unroll
        for (int p = 0; p < 2; ++p)
            #pragma unroll
            for (int j = 0; j < 8; ++j)
                ifr[p][j] = (bf16_t)((l4 * 8 + j == p * 16 + l15) ? 1.0f : 0.0f);
        #pragma unroll
        for (int m = 0; m < 4; ++m) {
            #pragma unroll
            for (int c = 0; c < 2; ++c) {
                const bf16x8 am = *(const bf16x8*)(A1mean +
                    (size_t)(m0 + m * 16 + l15) * 256 + (2 * w + c) * 32 + l4 * 8);
                acc[m][c * 2 + 0] = __builtin_amdgcn_mfma_f32_16x16x32_bf16(am, ifr[0], acc[m][c * 2 + 0], 0, 0, 0);
                acc[m][c * 2 + 1] = __builtin_amdgcn_mfma_f32_16x16x32_bf16(am, ifr[1], acc[m][c * 2 + 1], 0, 0, 0);
            }
        }
    }
    __syncthreads();   // dL complete — the only main barrier

    // main loop: ZERO barriers. B fragments direct global->VGPR; dL read-only.
    for (int kt = 0; kt < 8; ++kt) {
        const int k0 = kt * 32;
        bf16x8 bfr[4];
        #pragma unroll
        for (int nb = 0; nb < 4; ++nb)
            bfr[nb] = *(const bf16x8*)(W2 + (size_t)(w * 64 + nb * 16 + l15) * 256 + k0 + l4 * 8);
        bf16x8 af[4];
        #pragma unroll
        for (int m = 0; m < 4; ++m)
            af[m] = *(const bf16x8*)(&dL[((kt * 4 + l4) * 64 + m * 16 + l15) * 8]);
        #pragma unroll
        for (int m = 0; m < 4; ++m)
            #pragma unroll
            for (int nb = 0; nb < 4; ++nb)
                acc[m][nb] = __builtin_amdgcn_mfma_f32_16x16x32_bf16(af[m], bfr[nb], acc[m][nb], 0, 0, 0);
    }

    __syncthreads();   // dL dead before tt/part overlay

    bf16x8 owf[2];
    #pragma unroll
    for (int s = 0; s < 2; ++s) {
        #pragma unroll
        for (int j = 0; j < 8; ++j) owf[s][j] = (bf16_t)0.0f;
        if (l15 < 8)
            owf[s] = *(const bf16x8*)(owb + l15 * 256 + w * 64 + s * 32 + l4 * 8);
    }

    bf16_t* ttw = tt + w * 2048;   // private per-wave [8 kq][32 rows][8]
    #pragma unroll
    for (int h = 0; h < 2; ++h) {
        #pragma unroll
        for (int mm = 0; mm < 2; ++mm) {
            const int m = h * 2 + mm;
            #pragma unroll
            for (int nb = 0; nb < 4; ++nb) {
                const int col = nb * 16 + l15;
                const int kg = col >> 3, cj = col & 7;
                #pragma unroll
                for (int i = 0; i < 4; ++i) {
                    const int rl = mm * 16 + l4 * 4 + i;
                    ttw[(kg * 32 + rl) * 8 + cj] = (bf16_t)gelu_f(acc[m][nb][i]);
                }
            }
        }
        f32x4 accp[2];
        #pragma unroll
        for (int mb = 0; mb < 2; ++mb) {
            accp[mb][0] = 0.f; accp[mb][1] = 0.f; accp[mb][2] = 0.f; accp[mb][3] = 0.f;
            #pragma unroll
            for (int s = 0; s < 2; ++s) {
                const bf16x8 af = *(const bf16x8*)(&ttw[((s * 4 + l4) * 32 + mb * 16 + l15) * 8]);
                accp[mb] = __builtin_amdgcn_mfma_f32_16x16x32_bf16(af, owf[s], accp[mb], 0, 0, 0);
            }
        }
        __syncthreads();
        #pragma unroll
        for (int mb = 0; mb < 2; ++mb)
            #pragma unroll
            for (int i = 0; i < 4; ++i)
                part[(w * 32 + mb * 16 + l4 * 4 + i) * 16 + l15] = accp[mb][i];
        __syncthreads();
        {
            const int row = t >> 3, o = t & 7;
            const float v = part[(0 * 32 + row) * 16 + o] + part[(1 * 32 + row) * 16 + o]
                          + part[(2 * 32 + row) * 16 + o] + part[(3 * 32 + row) * 16 + o] + ob[o];
            out[(size_t)(m0 + h * 32 + row) * 8 + o] = v;
        }
    }
}

// ---------------- launch ----------------

extern "C" void kernel_launch(void* const* d_in, const int* in_sizes, int n_in,
                              void* d_out, int out_size, void* d_ws, size_t ws_size,
                              hipStream_t stream) {
    const float* data_x   = (const float*)d_in[0];
    const float* hidden_x = (const float*)d_in[1];
    const int* dh_src = (const int*)d_in[2];
    const int* dh_dst = (const int*)d_in[3];
    const int* hh_src = (const int*)d_in[4];
    const int* hh_dst = (const int*)d_in[5];
    const int* hd_src = (const int*)d_in[6];
    const int* hd_dst = (const int*)d_in[7];
    const float* enc_src_w = (const float*)d_in[8];
    const float* enc_src_b = (const float*)d_in[9];
    const float* enc_dst_w = (const float*)d_in[10];
    const float* enc_dst_b = (const float*)d_in[11];
    const float* enc_wl = (const float*)d_in[12];
    const float* enc_bl = (const float*)d_in[13];
    const float* enc_wr = (const float*)d_in[14];
    const float* proc_wl = (const float*)d_in[15];
    const float* proc_bl = (const float*)d_in[16];
    const float* proc_wr = (const float*)d_in[17];
    const float* proc_mlp_w = (const float*)d_in[18];
    const float* proc_mlp_b = (const float*)d_in[19];
    const float* dec_src_w = (const float*)d_in[20];
    const float* dec_src_b = (const float*)d_in[21];
    const float* dec_dst_w = (const float*)d_in[22];
    const float* dec_dst_b = (const float*)d_in[23];
    const float* dec_wl = (const float*)d_in[24];
    const float* dec_bl = (const float*)d_in[25];
    const float* dec_wr = (const float*)d_in[26];
    const float* out_w  = (const float*)d_in[27];
    const float* out_b  = (const float*)d_in[28];
    float* out = (float*)d_out;

    // ---- workspace ----
    bf16_t* h_a   = (bf16_t*)d_ws;                       // NHID*256
    bf16_t* h_b   = h_a + (size_t)NHID * 256;            // NHID*256
    bf16_t* h_c   = h_b + (size_t)NHID * 256;            // NHID*256
    bf16_t* h_msg = h_c + (size_t)NHID * 256;            // NDATA*256
    bf16_t* dmean = h_msg + (size_t)NDATA * 256;         // NDATA*256
    bf16_t* wbuf  = dmean + (size_t)NDATA * 256;         // 8*65536 + 4096
    int* cnt_all    = (int*)(wbuf + 8 * 65536 + 4096);   // 2*NHID+NDATA
    int* rp_all     = cnt_all + (2 * NHID + NDATA);      // 2*(NHID+1)+NDATA+1
    int* sorted_all = rp_all + (2 * NHID + NDATA + 3);   // 3*NEDGE
    int* blk_sums   = sorted_all + (size_t)3 * NEDGE;    // 192
    int* binA       = blk_sums + 192;                    // 384
    int2* pairs     = (int2*)(((uintptr_t)(binA + 384) + 15) & ~(uintptr_t)15);  // 3*NEDGE int2

    bf16_t* W_enc_wl  = wbuf + 0 * 65536;
    bf16_t* W_enc_wr  = wbuf + 1 * 65536;
    bf16_t* W_proc_wl = wbuf + 2 * 65536;
    bf16_t* W_proc_wr = wbuf + 3 * 65536;
    bf16_t* W_mlp     = wbuf + 4 * 65536;
    bf16_t* W_dec_src = wbuf + 5 * 65536;
    bf16_t* W_dec_wl  = wbuf + 6 * 65536;
    bf16_t* W_dec_wr  = wbuf + 7 * 65536;
    bf16_t* W_out     = wbuf + 8 * 65536;            // 8x256
    bf16_t* W_dd      = wbuf + 8 * 65536 + 2048;     // 256x8 (dec_dst_w bf16)

    const int* rp_dh = rp_all;
    const int* rp_hh = rp_all + NHID + 1;
    const int* rp_hd = rp_all + 2 * NHID + 2;
    const int* so_dh = sorted_all;
    const int* so_hh = sorted_all + NEDGE;
    const int* so_hd = sorted_all + 2 * (size_t)NEDGE;

    WPtrs wp;
    wp.p[0] = enc_wl;  wp.p[1] = enc_wr;  wp.p[2] = proc_wl; wp.p[3] = proc_wr;
    wp.p[4] = proc_mlp_w; wp.p[5] = dec_src_w; wp.p[6] = dec_wl; wp.p[7] = dec_wr;
    wp.p[8] = out_w; wp.p[9] = dec_dst_w;

    // ---- batched CSR build ----
    EdgePtrs ep;
    ep.src[0] = dh_src; ep.dst[0] = dh_dst;
    ep.src[1] = hh_src; ep.dst[1] = hh_dst;
    ep.src[2] = hd_src; ep.dst[2] = hd_dst;
    hipMemsetAsync(cnt_all, 0, (size_t)(2 * NHID + NDATA) * sizeof(int), stream);
    hist3<<<3 * 2048, 256, 0, stream>>>(ep, cnt_all);
    scan_blk3<<<192, 256, 0, stream>>>(cnt_all, rp_all, blk_sums);
    scan_add3<<<192, 256, 0, stream>>>(rp_all, blk_sums, rp_all, binA);
    partition3<<<3 * 128, 256, 0, stream>>>(ep, binA, pairs);
    binsort3<<<3 * 128, 256, 0, stream>>>(pairs, rp_all, sorted_all);

    // ---- cvt + encoders (merged) ----
    enc_cvt_both<<<4624, 256, 0, stream>>>(wp, wbuf,
                                           hidden_x, enc_dst_w, enc_dst_b, h_a,
                                           data_x, enc_src_w, enc_src_b, h_msg);
    csr_gather_mean<<<NHID / 4, 256, 0, stream>>>(h_msg, rp_dh, so_dh, h_b, NHID);
    // H1 = gelu(mean1@enc_wl^T + enc_bl + h_a@enc_wr^T) -> h_c
    mfma_gemm<1, 1><<<(NHID / 64) * 2, 256, 0, stream>>>(h_b, W_enc_wl, h_a, W_enc_wr, enc_bl, h_c);

    // ---- processor ----
    csr_gather_mean<<<NHID / 4, 256, 0, stream>>>(h_c, rp_hh, so_hh, h_a, NHID);
    // gelu(H2) -> h_b
    mfma_gemm<1, 1><<<(NHID / 64) * 2, 256, 0, stream>>>(h_a, W_proc_wl, h_c, W_proc_wr, proc_bl, h_b);
    // H3 -> h_a
    mfma_gemm<0, 1><<<(NHID / 64) * 2, 256, 0, stream>>>(h_b, W_mlp, nullptr, nullptr, proc_mlp_b, h_a);
    // chained: sW = gelu(H3@dec_src^T + b) @ dec_wl^T -> h_c
    gemm_chain2<<<NHID / 64, 256, 0, stream>>>(h_a, W_dec_src, dec_src_b, W_dec_wl, h_c);

    // ---- decoder: gather mean(sW), then fused final kernel (zero-barrier main loop) ----
    csr_gather_mean<<<NDATA / 4, 256, 0, stream>>>(h_c, rp_hd, so_hd, dmean, NDATA);
    dec_gemm_m<<<NDATA / 64, 256, 0, stream>>>(dmean, data_x, W_dd, dec_dst_b,
                                               W_dec_wr, dec_bl, W_out, out_b, out);
}

// Round 19
// 452.131 us; speedup vs baseline: 1.0061x; 1.0061x over previous
//
#include <hip/hip_runtime.h>
#include <stdint.h>

#define NDATA 131072
#define NHID  32768
#define NEDGE 524288

typedef __bf16 bf16_t;
typedef __bf16 bf16x4 __attribute__((ext_vector_type(4)));
typedef __bf16 bf16x8 __attribute__((ext_vector_type(8)));
typedef float  f32x4  __attribute__((ext_vector_type(4)));

__device__ __forceinline__ float gelu_f(float x) {
    return 0.5f * x * (1.0f + erff(x * 0.7071067811865476f));
}

// direct global->LDS 16B copy: dest = lds_base + lane*16 (HW contract)
__device__ __forceinline__ void glds16(const void* g, void* l) {
    auto* gp = reinterpret_cast<const __attribute__((address_space(1))) uint32_t*>(
        reinterpret_cast<uintptr_t>(g));
    auto* lp = reinterpret_cast<__attribute__((address_space(3))) uint32_t*>(
        reinterpret_cast<uintptr_t>(l));
    __builtin_amdgcn_global_load_lds(gp, lp, 16, 0, 0);
}

struct WPtrs { const float* p[10]; };

// ---------------- batched CSR build (3 graphs), two-level sort ----------------
struct EdgePtrs { const int* src[3]; const int* dst[3]; };

__device__ __forceinline__ int cnt_off_of(int g) { return g == 0 ? 0 : (g == 1 ? NHID : 2 * NHID); }
__device__ __forceinline__ int rp_off_of(int g)  { return g == 0 ? 0 : (g == 1 ? NHID + 1 : 2 * NHID + 2); }
__device__ __forceinline__ int shift_of(int g)   { return g == 2 ? 10 : 8; }   // 128 bins

__global__ __launch_bounds__(256)
void hist3(EdgePtrs ep, int* __restrict__ cnt_all) {
    const int g = blockIdx.x >> 11;
    const int i = ((blockIdx.x & 2047) << 8) + threadIdx.x;
    atomicAdd(&cnt_all[cnt_off_of(g) + ep.dst[g][i]], 1);
}

__global__ __launch_bounds__(256)
void scan_blk3(const int* __restrict__ cnt_all, int* __restrict__ pre_all,
               int* __restrict__ blk) {
    __shared__ int sh[256];
    const int bid = blockIdx.x;
    int g, local;
    if (bid < 32)      { g = 0; local = bid; }
    else if (bid < 64) { g = 1; local = bid - 32; }
    else               { g = 2; local = bid - 64; }
    const int t = threadIdx.x;
    const int cbase = cnt_off_of(g) + local * 1024 + t * 4;
    const int pbase = rp_off_of(g)  + local * 1024 + t * 4;
    int4 v = *(const int4*)(cnt_all + cbase);
    sh[t] = v.x + v.y + v.z + v.w;
    __syncthreads();
    for (int off = 1; off < 256; off <<= 1) {
        int other = 0;
        if (t >= off) other = sh[t - off];
        __syncthreads();
        if (t >= off) sh[t] += other;
        __syncthreads();
    }
    const int excl = (t == 0) ? 0 : sh[t - 1];
    int4 o;
    o.x = excl; o.y = o.x + v.x; o.z = o.y + v.y; o.w = o.z + v.z;
    *(int4*)(pre_all + pbase) = o;
    if (t == 255) blk[bid] = sh[255];
}

__global__ __launch_bounds__(256)
void scan_add3(const int* __restrict__ pre_all, const int* __restrict__ blk,
               int* __restrict__ rp_all, int* __restrict__ binA) {
    __shared__ int sh[256];
    const int bid = blockIdx.x;
    int g, local, gbase;
    if (bid < 32)      { g = 0; local = bid;      gbase = 0; }
    else if (bid < 64) { g = 1; local = bid - 32; gbase = 32; }
    else               { g = 2; local = bid - 64; gbase = 64; }
    const int t = threadIdx.x;
    int part = 0;
    if (t < local) part = blk[gbase + t];
    sh[t] = part;
    __syncthreads();
    for (int o2 = 128; o2 > 0; o2 >>= 1) {
        if (t < o2) sh[t] += sh[t + o2];
        __syncthreads();
    }
    const int off = sh[0];
    const int idx = local * 1024 + t * 4;
    const int pbase = rp_off_of(g) + idx;
    int4 v = *(const int4*)(pre_all + pbase);
    v.x += off; v.y += off; v.z += off; v.w += off;
    *(int4*)(rp_all + pbase) = v;
    const int bw = 1 << shift_of(g);
    if ((idx & (bw - 1)) == 0) binA[g * 128 + (idx >> shift_of(g))] = v.x;
    if (local == 0 && t == 0) {
        const int n = (g == 2) ? NDATA : NHID;
        rp_all[rp_off_of(g) + n] = NEDGE;
    }
}

__global__ __launch_bounds__(256)
void partition3(EdgePtrs ep, int* __restrict__ binA, int2* __restrict__ pairs) {
    __shared__ int hist[128], base[128], cur[128];
    const int g = blockIdx.x >> 7;
    const int blk = blockIdx.x & 127;
    const int t = threadIdx.x;
    const int shift = shift_of(g);
    const int e_base = blk * 4096;
    const int* src = ep.src[g];
    const int* dst = ep.dst[g];
    if (t < 128) { hist[t] = 0; cur[t] = 0; }
    __syncthreads();
    #pragma unroll
    for (int it = 0; it < 16; ++it) {
        const int d = dst[e_base + it * 256 + t];
        atomicAdd(&hist[d >> shift], 1);
    }
    __syncthreads();
    if (t < 128) base[t] = atomicAdd(&binA[g * 128 + t], hist[t]);
    __syncthreads();
    #pragma unroll
    for (int it = 0; it < 16; ++it) {
        const int e = e_base + it * 256 + t;
        const int s = src[e], d = dst[e];
        const int b = d >> shift;
        const int l = atomicAdd(&cur[b], 1);
        pairs[(size_t)g * NEDGE + base[b] + l] = make_int2(s, d);
    }
}

__global__ __launch_bounds__(256)
void binsort3(const int2* __restrict__ pairs, const int* __restrict__ rp_all,
              int* __restrict__ sorted_all) {
    __shared__ int cur[1024];
    const int g = blockIdx.x >> 7;
    const int b = blockIdx.x & 127;
    const int t = threadIdx.x;
    const int shift = shift_of(g);
    const int W = 1 << shift;
    const int d0 = b << shift;
    const int rpo = rp_off_of(g);
    for (int i = t; i < W; i += 256) cur[i] = rp_all[rpo + d0 + i];
    __syncthreads();
    const int e0 = rp_all[rpo + d0];
    const int e1 = rp_all[rpo + d0 + W];
    for (int e = e0 + t; e < e1; e += 256) {
        const int2 p = pairs[(size_t)g * NEDGE + e];
        const int pos = atomicAdd(&cur[p.y - d0], 1);
        sorted_all[(size_t)g * NEDGE + pos] = p.x;
    }
}

// ---------------- CSR aggregation (mean), bf16 features; 8/4/2-stride loops ----------------
__global__ __launch_bounds__(256)
void csr_gather_mean(const bf16_t* __restrict__ feat, const int* __restrict__ row_ptr,
                     const int* __restrict__ sorted_src, bf16_t* __restrict__ mean, int n) {
    const int lane = threadIdx.x & 63;
    const int half = lane >> 5;
    const int col8 = (lane & 31) * 8;
    const int w = blockIdx.x * 4 + (threadIdx.x >> 6);
    if (w >= n) return;
    const int e0 = row_ptr[w], e1 = row_ptr[w + 1];
    float acc[8] = {0.f, 0.f, 0.f, 0.f, 0.f, 0.f, 0.f, 0.f};
    int e = e0 + half;
    for (; e + 6 < e1; e += 8) {
        const int s0 = sorted_src[e],     s1 = sorted_src[e + 2];
        const int s2 = sorted_src[e + 4], s3 = sorted_src[e + 6];
        const bf16x8 v0 = *(const bf16x8*)(feat + (size_t)s0 * 256 + col8);
        const bf16x8 v1 = *(const bf16x8*)(feat + (size_t)s1 * 256 + col8);
        const bf16x8 v2 = *(const bf16x8*)(feat + (size_t)s2 * 256 + col8);
        const bf16x8 v3 = *(const bf16x8*)(feat + (size_t)s3 * 256 + col8);
        #pragma unroll
        for (int j = 0; j < 8; ++j)
            acc[j] += ((float)v0[j] + (float)v1[j]) + ((float)v2[j] + (float)v3[j]);
    }
    for (; e + 2 < e1; e += 4) {
        const int s0 = sorted_src[e], s1 = sorted_src[e + 2];
        const bf16x8 v0 = *(const bf16x8*)(feat + (size_t)s0 * 256 + col8);
        const bf16x8 v1 = *(const bf16x8*)(feat + (size_t)s1 * 256 + col8);
        #pragma unroll
        for (int j = 0; j < 8; ++j) acc[j] += (float)v0[j] + (float)v1[j];
    }
    for (; e < e1; e += 2) {
        const int s0 = sorted_src[e];
        const bf16x8 v0 = *(const bf16x8*)(feat + (size_t)s0 * 256 + col8);
        #pragma unroll
        for (int j = 0; j < 8; ++j) acc[j] += (float)v0[j];
    }
    #pragma unroll
    for (int j = 0; j < 8; ++j) acc[j] += __shfl_xor(acc[j], 32, 64);
    if (half == 0) {
        const float ic = 1.0f / fmaxf((float)(e1 - e0), 1.0f);
        bf16x8 r;
        #pragma unroll
        for (int j = 0; j < 8; ++j) r[j] = (bf16_t)(acc[j] * ic);
        *(bf16x8*)(mean + (size_t)w * 256 + col8) = r;
    }
}

// ---------------- merged cvt + small-K encoders ----------------
// blocks [0,2064): weight cvt; [2064,2576): K3/NHID; [2576,4624): K8/NDATA
__global__ __launch_bounds__(256)
void enc_cvt_both(WPtrs wp, bf16_t* __restrict__ wout,
                  const float* __restrict__ hx, const float* __restrict__ w3,
                  const float* __restrict__ b3, bf16_t* __restrict__ out3,
                  const float* __restrict__ dx, const float* __restrict__ w8,
                  const float* __restrict__ b8, bf16_t* __restrict__ out8) {
    __shared__ float ws[8 * 256];
    __shared__ float bs[256];
    const int t = threadIdx.x;
    if (blockIdx.x < 2064) {
        const int i = blockIdx.x * 256 + t;
        if (i < 8 * 65536) {
            const int wsel = i >> 16, off = i & 65535;
            wout[i] = (bf16_t)wp.p[wsel][off];
        } else if (i < 8 * 65536 + 2048) {
            wout[i] = (bf16_t)wp.p[8][i - 8 * 65536];
        } else {
            wout[i] = (bf16_t)wp.p[9][i - (8 * 65536 + 2048)];
        }
        return;
    }
    const int bid = blockIdx.x - 2064;
    const bool is8 = (bid >= 512);
    if (is8) {
        #pragma unroll
        for (int j = 0; j < 8; ++j) ws[j * 256 + t] = w8[t * 8 + j];
        bs[t] = b8[t];
    } else {
        #pragma unroll
        for (int j = 0; j < 3; ++j) ws[j * 256 + t] = w3[t * 3 + j];
        bs[t] = b3[t];
    }
    __syncthreads();
    const int lane = t & 63, wv = t >> 6;
    const int f0 = lane * 4;
    const float4 b4 = *(const float4*)(&bs[f0]);
    if (!is8) {
        for (int node = bid * 4 + wv; node < NHID; node += 512 * 4) {
            const float* xr = hx + (size_t)node * 3;
            float xv[3];
            #pragma unroll
            for (int j = 0; j < 3; ++j) xv[j] = xr[j];
            float a0 = b4.x, a1 = b4.y, a2 = b4.z, a3 = b4.w;
            #pragma unroll
            for (int j = 0; j < 3; ++j) {
                const float4 w4 = *(const float4*)(&ws[j * 256 + f0]);
                a0 += xv[j] * w4.x; a1 += xv[j] * w4.y;
                a2 += xv[j] * w4.z; a3 += xv[j] * w4.w;
            }
            bf16x4 r;
            r[0] = (bf16_t)gelu_f(a0); r[1] = (bf16_t)gelu_f(a1);
            r[2] = (bf16_t)gelu_f(a2); r[3] = (bf16_t)gelu_f(a3);
            *(bf16x4*)(out3 + (size_t)node * 256 + f0) = r;
        }
    } else {
        for (int node = (bid - 512) * 4 + wv; node < NDATA; node += 2048 * 4) {
            const float* xr = dx + (size_t)node * 8;
            float xv[8];
            #pragma unroll
            for (int j = 0; j < 8; ++j) xv[j] = xr[j];
            float a0 = b4.x, a1 = b4.y, a2 = b4.z, a3 = b4.w;
            #pragma unroll
            for (int j = 0; j < 8; ++j) {
                const float4 w4 = *(const float4*)(&ws[j * 256 + f0]);
                a0 += xv[j] * w4.x; a1 += xv[j] * w4.y;
                a2 += xv[j] * w4.z; a3 += xv[j] * w4.w;
            }
            bf16x4 r;
            r[0] = (bf16_t)gelu_f(a0); r[1] = (bf16_t)gelu_f(a1);
            r[2] = (bf16_t)gelu_f(a2); r[3] = (bf16_t)gelu_f(a3);
            *(bf16x4*)(out8 + (size_t)node * 256 + f0) = r;
        }
    }
}

// ---------------- MFMA bf16 GEMM — 64x128 tile ----------------
template<int DUAL, int ACT>
__global__ __launch_bounds__(256)
void mfma_gemm(const bf16_t* __restrict__ A1, const bf16_t* __restrict__ W1,
               const bf16_t* __restrict__ A2, const bf16_t* __restrict__ W2,
               const float* __restrict__ bias, bf16_t* __restrict__ C) {
    __shared__ bf16_t As[4 * 64 * 8];    // 4 KB
    __shared__ bf16_t Bs[4 * 128 * 8];   // 8 KB
    const int t = threadIdx.x;
    const int w = t >> 6, lane = t & 63;
    const int l15 = lane & 15, l4 = lane >> 4;
    const int m0 = (blockIdx.x >> 1) * 64;
    const int n0 = (blockIdx.x & 1) * 128;

    f32x4 acc[4][2];
    #pragma unroll
    for (int nb = 0; nb < 2; ++nb) {
        const float bv = bias ? bias[n0 + w * 32 + nb * 16 + l15] : 0.0f;
        #pragma unroll
        for (int m = 0; m < 4; ++m) {
            acc[m][nb][0] = bv; acc[m][nb][1] = bv; acc[m][nb][2] = bv; acc[m][nb][3] = bv;
        }
    }

    #pragma unroll
    for (int p = 0; p <= DUAL; ++p) {
        const bf16_t* Ap = p ? A2 : A1;
        const bf16_t* Wp = p ? W2 : W1;
        for (int kt = 0; kt < 8; ++kt) {
            const int k0 = kt * 32;
            __syncthreads();
            glds16(Ap + (size_t)(m0 + lane) * 256 + k0 + w * 8, &As[(w * 64) * 8]);
            glds16(Wp + (size_t)(n0 + lane) * 256 + k0 + w * 8, &Bs[(w * 128) * 8]);
            glds16(Wp + (size_t)(n0 + 64 + lane) * 256 + k0 + w * 8, &Bs[(w * 128 + 64) * 8]);
            __syncthreads();
            bf16x8 af[4], bfr[2];
            #pragma unroll
            for (int m = 0; m < 4; ++m)
                af[m] = *(const bf16x8*)(&As[(l4 * 64 + m * 16 + l15) * 8]);
            #pragma unroll
            for (int nb = 0; nb < 2; ++nb)
                bfr[nb] = *(const bf16x8*)(&Bs[(l4 * 128 + w * 32 + nb * 16 + l15) * 8]);
            #pragma unroll
            for (int m = 0; m < 4; ++m)
                #pragma unroll
                for (int nb = 0; nb < 2; ++nb)
                    acc[m][nb] = __builtin_amdgcn_mfma_f32_16x16x32_bf16(af[m], bfr[nb], acc[m][nb], 0, 0, 0);
        }
    }

    #pragma unroll
    for (int m = 0; m < 4; ++m) {
        #pragma unroll
        for (int nb = 0; nb < 2; ++nb) {
            const int col = n0 + w * 32 + nb * 16 + l15;
            #pragma unroll
            for (int i = 0; i < 4; ++i) {
                const int row = m0 + m * 16 + l4 * 4 + i;
                const float v = acc[m][nb][i];
                C[(size_t)row * 256 + col] = (bf16_t)(ACT ? gelu_f(v) : v);
            }
        }
    }
}

// ---------------- chained dual GEMM: C = (gelu(b1 + A1@W1^T)) @ W2^T ----------------
__global__ __launch_bounds__(256)
void gemm_chain2(const bf16_t* __restrict__ A1, const bf16_t* __restrict__ W1,
                 const float* __restrict__ b1, const bf16_t* __restrict__ W2,
                 bf16_t* __restrict__ C) {
    __shared__ bf16_t As[4 * 64 * 8];     // 4 KB
    __shared__ bf16_t Bs[4 * 256 * 8];    // 16 KB
    __shared__ bf16_t sL[32 * 64 * 8];    // 32 KB
    const int t = threadIdx.x;
    const int w = t >> 6, lane = t & 63;
    const int l15 = lane & 15, l4 = lane >> 4;
    const int m0 = blockIdx.x * 64;

    f32x4 acc[4][4];
    #pragma unroll
    for (int nb = 0; nb < 4; ++nb) {
        const float bv = b1[w * 64 + nb * 16 + l15];
        #pragma unroll
        for (int m = 0; m < 4; ++m) {
            acc[m][nb][0] = bv; acc[m][nb][1] = bv; acc[m][nb][2] = bv; acc[m][nb][3] = bv;
        }
    }

    for (int kt = 0; kt < 8; ++kt) {
        const int k0 = kt * 32;
        __syncthreads();
        glds16(A1 + (size_t)(m0 + lane) * 256 + k0 + w * 8, &As[(w * 64) * 8]);
        #pragma unroll
        for (int q = 0; q < 4; ++q)
            glds16(W1 + (size_t)(w * 64 + lane) * 256 + k0 + q * 8,
                   &Bs[(q * 256 + w * 64) * 8]);
        __syncthreads();
        bf16x8 af[4], bfr[4];
        #pragma unroll
        for (int m = 0; m < 4; ++m)
            af[m] = *(const bf16x8*)(&As[(l4 * 64 + m * 16 + l15) * 8]);
        #pragma unroll
        for (int nb = 0; nb < 4; ++nb)
            bfr[nb] = *(const bf16x8*)(&Bs[(l4 * 256 + w * 64 + nb * 16 + l15) * 8]);
        #pragma unroll
        for (int m = 0; m < 4; ++m)
            #pragma unroll
            for (int nb = 0; nb < 4; ++nb)
                acc[m][nb] = __builtin_amdgcn_mfma_f32_16x16x32_bf16(af[m], bfr[nb], acc[m][nb], 0, 0, 0);
    }
    #pragma unroll
    for (int m = 0; m < 4; ++m) {
        #pragma unroll
        for (int nb = 0; nb < 4; ++nb) {
            const int col = w * 64 + nb * 16 + l15;
            const int kq = col >> 3, cj = col & 7;
            #pragma unroll
            for (int i = 0; i < 4; ++i) {
                const int row = m * 16 + l4 * 4 + i;
                sL[(kq * 64 + row) * 8 + cj] = (bf16_t)gelu_f(acc[m][nb][i]);
            }
            acc[m][nb][0] = 0.f; acc[m][nb][1] = 0.f; acc[m][nb][2] = 0.f; acc[m][nb][3] = 0.f;
        }
    }
    __syncthreads();

    for (int kt = 0; kt < 8; ++kt) {
        const int k0 = kt * 32;
        __syncthreads();
        #pragma unroll
        for (int q = 0; q < 4; ++q)
            glds16(W2 + (size_t)(w * 64 + lane) * 256 + k0 + q * 8,
                   &Bs[(q * 256 + w * 64) * 8]);
        __syncthreads();
        bf16x8 af[4], bfr[4];
        #pragma unroll
        for (int m = 0; m < 4; ++m)
            af[m] = *(const bf16x8*)(&sL[((kt * 4 + l4) * 64 + m * 16 + l15) * 8]);
        #pragma unroll
        for (int nb = 0; nb < 4; ++nb)
            bfr[nb] = *(const bf16x8*)(&Bs[(l4 * 256 + w * 64 + nb * 16 + l15) * 8]);
        #pragma unroll
        for (int m = 0; m < 4; ++m)
            #pragma unroll
            for (int nb = 0; nb < 4; ++nb)
                acc[m][nb] = __builtin_amdgcn_mfma_f32_16x16x32_bf16(af[m], bfr[nb], acc[m][nb], 0, 0, 0);
    }

    #pragma unroll
    for (int m = 0; m < 4; ++m) {
        #pragma unroll
        for (int nb = 0; nb < 4; ++nb) {
            const int col = w * 64 + nb * 16 + l15;
            #pragma unroll
            for (int i = 0; i < 4; ++i) {
                const int row = m0 + m * 16 + l4 * 4 + i;
                C[(size_t)row * 256 + col] = (bf16_t)acc[m][nb][i];
            }
        }
    }
}

// ---------------- decoder: t = gelu(dec_bl + mean(sW) + d@W2^T), out = t@ow^T + ob ----------------
// dL precomputed once (1 barrier). Main loop: coalesced glds into WAVE-PRIVATE Bs +
// per-wave vmcnt fence — NO block barriers. mean-add via identity-MFMA.
__global__ __launch_bounds__(256)
void dec_gemm_m(const bf16_t* __restrict__ A1mean,
                const float* __restrict__ xdat, const bf16_t* __restrict__ wdb,
                const float* __restrict__ bd, const bf16_t* __restrict__ W2,
                const float* __restrict__ bias, const bf16_t* __restrict__ owb,
                const float* __restrict__ ob, float* __restrict__ out) {
    __shared__ __align__(16) char smem[49152];
    bf16_t* dL = (bf16_t*)smem;                // 32 KB [32 kq][64 rows][8] — full d tile
    bf16_t* Bs = (bf16_t*)(smem + 32768);      // 16 KB [4 kq][256 n][8], rows wave-private
    // epilogue overlays (dL dead):
    bf16_t* tt   = (bf16_t*)smem;              // 16 KB
    float*  part = (float*)(smem + 16384);     // 8 KB

    const int t = threadIdx.x;
    const int w = t >> 6, lane = t & 63;
    const int l15 = lane & 15, l4 = lane >> 4;
    const int m0 = blockIdx.x * 64;

    // x A-fragment for the K=8 d-MFMA (lanes l4>0 hold zeros)
    bf16x8 af_x;
    #pragma unroll
    for (int j = 0; j < 8; ++j) af_x[j] = (bf16_t)0.0f;
    if (l4 == 0) {
        const float* xrp = xdat + (size_t)(m0 + w * 16 + l15) * 8;
        const float4 xa = *(const float4*)(xrp);
        const float4 xb = *(const float4*)(xrp + 4);
        af_x[0] = (bf16_t)xa.x; af_x[1] = (bf16_t)xa.y; af_x[2] = (bf16_t)xa.z; af_x[3] = (bf16_t)xa.w;
        af_x[4] = (bf16_t)xb.x; af_x[5] = (bf16_t)xb.y; af_x[6] = (bf16_t)xb.z; af_x[7] = (bf16_t)xb.w;
    }

    // d-phase: wave w computes rows w*16..w*16+15, all 256 cols, into dL
    #pragma unroll
    for (int cb = 0; cb < 16; ++cb) {
        const int col = cb * 16 + l15;
        f32x4 ad;
        const float bv = bd[col];
        ad[0] = bv; ad[1] = bv; ad[2] = bv; ad[3] = bv;
        bf16x8 bf_d;
        #pragma unroll
        for (int j = 0; j < 8; ++j) bf_d[j] = (bf16_t)0.0f;
        if (l4 == 0) bf_d = *(const bf16x8*)(wdb + col * 8);
        ad = __builtin_amdgcn_mfma_f32_16x16x32_bf16(af_x, bf_d, ad, 0, 0, 0);
        const int kq = col >> 3, jj = col & 7;
        #pragma unroll
        for (int i = 0; i < 4; ++i)
            dL[(kq * 64 + w * 16 + l4 * 4 + i) * 8 + jj] = (bf16_t)gelu_f(ad[i]);
    }

    // acc init: bias + mean(sW) via identity-MFMA (overlaps d-phase latency)
    f32x4 acc[4][4];
    #pragma unroll
    for (int nb = 0; nb < 4; ++nb) {
        const float bv = bias[w * 64 + nb * 16 + l15];
        #pragma unroll
        for (int m = 0; m < 4; ++m) {
            acc[m][nb][0] = bv; acc[m][nb][1] = bv; acc[m][nb][2] = bv; acc[m][nb][3] = bv;
        }
    }
    {
        bf16x8 ifr[2];
        #pragma unroll
        for (int p = 0; p < 2; ++p)
            #pragma unroll
            for (int j = 0; j < 8; ++j)
                ifr[p][j] = (bf16_t)((l4 * 8 + j == p * 16 + l15) ? 1.0f : 0.0f);
        #pragma unroll
        for (int m = 0; m < 4; ++m) {
            #pragma unroll
            for (int c = 0; c < 2; ++c) {
                const bf16x8 am = *(const bf16x8*)(A1mean +
                    (size_t)(m0 + m * 16 + l15) * 256 + (2 * w + c) * 32 + l4 * 8);
                acc[m][c * 2 + 0] = __builtin_amdgcn_mfma_f32_16x16x32_bf16(am, ifr[0], acc[m][c * 2 + 0], 0, 0, 0);
                acc[m][c * 2 + 1] = __builtin_amdgcn_mfma_f32_16x16x32_bf16(am, ifr[1], acc[m][c * 2 + 1], 0, 0, 0);
            }
        }
    }
    __syncthreads();   // dL complete — the only main barrier

    // main loop: NO block barriers. Bs rows are wave-private (stage == read range);
    // per-wave vmcnt(0) orders each wave's glds against its own ds_reads.
    for (int kt = 0; kt < 8; ++kt) {
        const int k0 = kt * 32;
        #pragma unroll
        for (int q = 0; q < 4; ++q)
            glds16(W2 + (size_t)(w * 64 + lane) * 256 + k0 + q * 8,
                   &Bs[(q * 256 + w * 64) * 8]);
        asm volatile("s_waitcnt vmcnt(0)" ::: "memory");
        bf16x8 af[4], bfr[4];
        #pragma unroll
        for (int m = 0; m < 4; ++m)
            af[m] = *(const bf16x8*)(&dL[((kt * 4 + l4) * 64 + m * 16 + l15) * 8]);
        #pragma unroll
        for (int nb = 0; nb < 4; ++nb)
            bfr[nb] = *(const bf16x8*)(&Bs[(l4 * 256 + w * 64 + nb * 16 + l15) * 8]);
        #pragma unroll
        for (int m = 0; m < 4; ++m)
            #pragma unroll
            for (int nb = 0; nb < 4; ++nb)
                acc[m][nb] = __builtin_amdgcn_mfma_f32_16x16x32_bf16(af[m], bfr[nb], acc[m][nb], 0, 0, 0);
    }

    __syncthreads();   // dL/Bs dead before tt/part overlay

    bf16x8 owf[2];
    #pragma unroll
    for (int s = 0; s < 2; ++s) {
        #pragma unroll
        for (int j = 0; j < 8; ++j) owf[s][j] = (bf16_t)0.0f;
        if (l15 < 8)
            owf[s] = *(const bf16x8*)(owb + l15 * 256 + w * 64 + s * 32 + l4 * 8);
    }

    bf16_t* ttw = tt + w * 2048;   // private per-wave [8 kq][32 rows][8]
    #pragma unroll
    for (int h = 0; h < 2; ++h) {
        #pragma unroll
        for (int mm = 0; mm < 2; ++mm) {
            const int m = h * 2 + mm;
            #pragma unroll
            for (int nb = 0; nb < 4; ++nb) {
                const int col = nb * 16 + l15;
                const int kg = col >> 3, cj = col & 7;
                #pragma unroll
                for (int i = 0; i < 4; ++i) {
                    const int rl = mm * 16 + l4 * 4 + i;
                    ttw[(kg * 32 + rl) * 8 + cj] = (bf16_t)gelu_f(acc[m][nb][i]);
                }
            }
        }
        f32x4 accp[2];
        #pragma unroll
        for (int mb = 0; mb < 2; ++mb) {
            accp[mb][0] = 0.f; accp[mb][1] = 0.f; accp[mb][2] = 0.f; accp[mb][3] = 0.f;
            #pragma unroll
            for (int s = 0; s < 2; ++s) {
                const bf16x8 af = *(const bf16x8*)(&ttw[((s * 4 + l4) * 32 + mb * 16 + l15) * 8]);
                accp[mb] = __builtin_amdgcn_mfma_f32_16x16x32_bf16(af, owf[s], accp[mb], 0, 0, 0);
            }
        }
        __syncthreads();
        #pragma unroll
        for (int mb = 0; mb < 2; ++mb)
            #pragma unroll
            for (int i = 0; i < 4; ++i)
                part[(w * 32 + mb * 16 + l4 * 4 + i) * 16 + l15] = accp[mb][i];
        __syncthreads();
        {
            const int row = t >> 3, o = t & 7;
            const float v = part[(0 * 32 + row) * 16 + o] + part[(1 * 32 + row) * 16 + o]
                          + part[(2 * 32 + row) * 16 + o] + part[(3 * 32 + row) * 16 + o] + ob[o];
            out[(size_t)(m0 + h * 32 + row) * 8 + o] = v;
        }
    }
}

// ---------------- launch ----------------

extern "C" void kernel_launch(void* const* d_in, const int* in_sizes, int n_in,
                              void* d_out, int out_size, void* d_ws, size_t ws_size,
                              hipStream_t stream) {
    const float* data_x   = (const float*)d_in[0];
    const float* hidden_x = (const float*)d_in[1];
    const int* dh_src = (const int*)d_in[2];
    const int* dh_dst = (const int*)d_in[3];
    const int* hh_src = (const int*)d_in[4];
    const int* hh_dst = (const int*)d_in[5];
    const int* hd_src = (const int*)d_in[6];
    const int* hd_dst = (const int*)d_in[7];
    const float* enc_src_w = (const float*)d_in[8];
    const float* enc_src_b = (const float*)d_in[9];
    const float* enc_dst_w = (const float*)d_in[10];
    const float* enc_dst_b = (const float*)d_in[11];
    const float* enc_wl = (const float*)d_in[12];
    const float* enc_bl = (const float*)d_in[13];
    const float* enc_wr = (const float*)d_in[14];
    const float* proc_wl = (const float*)d_in[15];
    const float* proc_bl = (const float*)d_in[16];
    const float* proc_wr = (const float*)d_in[17];
    const float* proc_mlp_w = (const float*)d_in[18];
    const float* proc_mlp_b = (const float*)d_in[19];
    const float* dec_src_w = (const float*)d_in[20];
    const float* dec_src_b = (const float*)d_in[21];
    const float* dec_dst_w = (const float*)d_in[22];
    const float* dec_dst_b = (const float*)d_in[23];
    const float* dec_wl = (const float*)d_in[24];
    const float* dec_bl = (const float*)d_in[25];
    const float* dec_wr = (const float*)d_in[26];
    const float* out_w  = (const float*)d_in[27];
    const float* out_b  = (const float*)d_in[28];
    float* out = (float*)d_out;

    // ---- workspace ----
    bf16_t* h_a   = (bf16_t*)d_ws;                       // NHID*256
    bf16_t* h_b   = h_a + (size_t)NHID * 256;            // NHID*256
    bf16_t* h_c   = h_b + (size_t)NHID * 256;            // NHID*256
    bf16_t* h_msg = h_c + (size_t)NHID * 256;            // NDATA*256
    bf16_t* dmean = h_msg + (size_t)NDATA * 256;         // NDATA*256
    bf16_t* wbuf  = dmean + (size_t)NDATA * 256;         // 8*65536 + 4096
    int* cnt_all    = (int*)(wbuf + 8 * 65536 + 4096);   // 2*NHID+NDATA
    int* rp_all     = cnt_all + (2 * NHID + NDATA);      // 2*(NHID+1)+NDATA+1
    int* sorted_all = rp_all + (2 * NHID + NDATA + 3);   // 3*NEDGE
    int* blk_sums   = sorted_all + (size_t)3 * NEDGE;    // 192
    int* binA       = blk_sums + 192;                    // 384
    int2* pairs     = (int2*)(((uintptr_t)(binA + 384) + 15) & ~(uintptr_t)15);  // 3*NEDGE int2

    bf16_t* W_enc_wl  = wbuf + 0 * 65536;
    bf16_t* W_enc_wr  = wbuf + 1 * 65536;
    bf16_t* W_proc_wl = wbuf + 2 * 65536;
    bf16_t* W_proc_wr = wbuf + 3 * 65536;
    bf16_t* W_mlp     = wbuf + 4 * 65536;
    bf16_t* W_dec_src = wbuf + 5 * 65536;
    bf16_t* W_dec_wl  = wbuf + 6 * 65536;
    bf16_t* W_dec_wr  = wbuf + 7 * 65536;
    bf16_t* W_out     = wbuf + 8 * 65536;            // 8x256
    bf16_t* W_dd      = wbuf + 8 * 65536 + 2048;     // 256x8 (dec_dst_w bf16)

    const int* rp_dh = rp_all;
    const int* rp_hh = rp_all + NHID + 1;
    const int* rp_hd = rp_all + 2 * NHID + 2;
    const int* so_dh = sorted_all;
    const int* so_hh = sorted_all + NEDGE;
    const int* so_hd = sorted_all + 2 * (size_t)NEDGE;

    WPtrs wp;
    wp.p[0] = enc_wl;  wp.p[1] = enc_wr;  wp.p[2] = proc_wl; wp.p[3] = proc_wr;
    wp.p[4] = proc_mlp_w; wp.p[5] = dec_src_w; wp.p[6] = dec_wl; wp.p[7] = dec_wr;
    wp.p[8] = out_w; wp.p[9] = dec_dst_w;

    // ---- batched CSR build ----
    EdgePtrs ep;
    ep.src[0] = dh_src; ep.dst[0] = dh_dst;
    ep.src[1] = hh_src; ep.dst[1] = hh_dst;
    ep.src[2] = hd_src; ep.dst[2] = hd_dst;
    hipMemsetAsync(cnt_all, 0, (size_t)(2 * NHID + NDATA) * sizeof(int), stream);
    hist3<<<3 * 2048, 256, 0, stream>>>(ep, cnt_all);
    scan_blk3<<<192, 256, 0, stream>>>(cnt_all, rp_all, blk_sums);
    scan_add3<<<192, 256, 0, stream>>>(rp_all, blk_sums, rp_all, binA);
    partition3<<<3 * 128, 256, 0, stream>>>(ep, binA, pairs);
    binsort3<<<3 * 128, 256, 0, stream>>>(pairs, rp_all, sorted_all);

    // ---- cvt + encoders (merged) ----
    enc_cvt_both<<<4624, 256, 0, stream>>>(wp, wbuf,
                                           hidden_x, enc_dst_w, enc_dst_b, h_a,
                                           data_x, enc_src_w, enc_src_b, h_msg);
    csr_gather_mean<<<NHID / 4, 256, 0, stream>>>(h_msg, rp_dh, so_dh, h_b, NHID);
    // H1 = gelu(mean1@enc_wl^T + enc_bl + h_a@enc_wr^T) -> h_c
    mfma_gemm<1, 1><<<(NHID / 64) * 2, 256, 0, stream>>>(h_b, W_enc_wl, h_a, W_enc_wr, enc_bl, h_c);

    // ---- processor ----
    csr_gather_mean<<<NHID / 4, 256, 0, stream>>>(h_c, rp_hh, so_hh, h_a, NHID);
    // gelu(H2) -> h_b
    mfma_gemm<1, 1><<<(NHID / 64) * 2, 256, 0, stream>>>(h_a, W_proc_wl, h_c, W_proc_wr, proc_bl, h_b);
    // H3 -> h_a
    mfma_gemm<0, 1><<<(NHID / 64) * 2, 256, 0, stream>>>(h_b, W_mlp, nullptr, nullptr, proc_mlp_b, h_a);
    // chained: sW = gelu(H3@dec_src^T + b) @ dec_wl^T -> h_c
    gemm_chain2<<<NHID / 64, 256, 0, stream>>>(h_a, W_dec_src, dec_src_b, W_dec_wl, h_c);

    // ---- decoder: gather mean(sW), then fused final kernel (wave-private fence loop) ----
    csr_gather_mean<<<NDATA / 4, 256, 0, stream>>>(h_c, rp_hd, so_hd, dmean, NDATA);
    dec_gemm_m<<<NDATA / 64, 256, 0, stream>>>(dmean, data_x, W_dd, dec_dst_b,
                                               W_dec_wr, dec_bl, W_out, out_b, out);
}

// Round 20
// 441.513 us; speedup vs baseline: 1.0303x; 1.0240x over previous
//
#include <hip/hip_runtime.h>
#include <stdint.h>

#define NDATA 131072
#define NHID  32768
#define NEDGE 524288

typedef __bf16 bf16_t;
typedef __bf16 bf16x4 __attribute__((ext_vector_type(4)));
typedef __bf16 bf16x8 __attribute__((ext_vector_type(8)));
typedef float  f32x4  __attribute__((ext_vector_type(4)));

__device__ __forceinline__ float gelu_f(float x) {
    return 0.5f * x * (1.0f + erff(x * 0.7071067811865476f));
}

// direct global->LDS 16B copy: dest = lds_base + lane*16 (HW contract)
__device__ __forceinline__ void glds16(const void* g, void* l) {
    auto* gp = reinterpret_cast<const __attribute__((address_space(1))) uint32_t*>(
        reinterpret_cast<uintptr_t>(g));
    auto* lp = reinterpret_cast<__attribute__((address_space(3))) uint32_t*>(
        reinterpret_cast<uintptr_t>(l));
    __builtin_amdgcn_global_load_lds(gp, lp, 16, 0, 0);
}

struct WPtrs { const float* p[10]; };

// ---------------- batched CSR build (3 graphs), two-level sort ----------------
struct EdgePtrs { const int* src[3]; const int* dst[3]; };

__device__ __forceinline__ int cnt_off_of(int g) { return g == 0 ? 0 : (g == 1 ? NHID : 2 * NHID); }
__device__ __forceinline__ int rp_off_of(int g)  { return g == 0 ? 0 : (g == 1 ? NHID + 1 : 2 * NHID + 2); }
__device__ __forceinline__ int shift_of(int g)   { return g == 2 ? 10 : 8; }   // 128 bins

__global__ __launch_bounds__(256)
void hist3(EdgePtrs ep, int* __restrict__ cnt_all) {
    const int g = blockIdx.x >> 11;
    const int i = ((blockIdx.x & 2047) << 8) + threadIdx.x;
    atomicAdd(&cnt_all[cnt_off_of(g) + ep.dst[g][i]], 1);
}

__global__ __launch_bounds__(256)
void scan_blk3(const int* __restrict__ cnt_all, int* __restrict__ pre_all,
               int* __restrict__ blk) {
    __shared__ int sh[256];
    const int bid = blockIdx.x;
    int g, local;
    if (bid < 32)      { g = 0; local = bid; }
    else if (bid < 64) { g = 1; local = bid - 32; }
    else               { g = 2; local = bid - 64; }
    const int t = threadIdx.x;
    const int cbase = cnt_off_of(g) + local * 1024 + t * 4;
    const int pbase = rp_off_of(g)  + local * 1024 + t * 4;
    int4 v = *(const int4*)(cnt_all + cbase);
    sh[t] = v.x + v.y + v.z + v.w;
    __syncthreads();
    for (int off = 1; off < 256; off <<= 1) {
        int other = 0;
        if (t >= off) other = sh[t - off];
        __syncthreads();
        if (t >= off) sh[t] += other;
        __syncthreads();
    }
    const int excl = (t == 0) ? 0 : sh[t - 1];
    int4 o;
    o.x = excl; o.y = o.x + v.x; o.z = o.y + v.y; o.w = o.z + v.z;
    *(int4*)(pre_all + pbase) = o;
    if (t == 255) blk[bid] = sh[255];
}

__global__ __launch_bounds__(256)
void scan_add3(const int* __restrict__ pre_all, const int* __restrict__ blk,
               int* __restrict__ rp_all, int* __restrict__ binA) {
    __shared__ int sh[256];
    const int bid = blockIdx.x;
    int g, local, gbase;
    if (bid < 32)      { g = 0; local = bid;      gbase = 0; }
    else if (bid < 64) { g = 1; local = bid - 32; gbase = 32; }
    else               { g = 2; local = bid - 64; gbase = 64; }
    const int t = threadIdx.x;
    int part = 0;
    if (t < local) part = blk[gbase + t];
    sh[t] = part;
    __syncthreads();
    for (int o2 = 128; o2 > 0; o2 >>= 1) {
        if (t < o2) sh[t] += sh[t + o2];
        __syncthreads();
    }
    const int off = sh[0];
    const int idx = local * 1024 + t * 4;
    const int pbase = rp_off_of(g) + idx;
    int4 v = *(const int4*)(pre_all + pbase);
    v.x += off; v.y += off; v.z += off; v.w += off;
    *(int4*)(rp_all + pbase) = v;
    const int bw = 1 << shift_of(g);
    if ((idx & (bw - 1)) == 0) binA[g * 128 + (idx >> shift_of(g))] = v.x;
    if (local == 0 && t == 0) {
        const int n = (g == 2) ? NDATA : NHID;
        rp_all[rp_off_of(g) + n] = NEDGE;
    }
}

__global__ __launch_bounds__(256)
void partition3(EdgePtrs ep, int* __restrict__ binA, int2* __restrict__ pairs) {
    __shared__ int hist[128], base[128], cur[128];
    const int g = blockIdx.x >> 7;
    const int blk = blockIdx.x & 127;
    const int t = threadIdx.x;
    const int shift = shift_of(g);
    const int e_base = blk * 4096;
    const int* src = ep.src[g];
    const int* dst = ep.dst[g];
    if (t < 128) { hist[t] = 0; cur[t] = 0; }
    __syncthreads();
    #pragma unroll
    for (int it = 0; it < 16; ++it) {
        const int d = dst[e_base + it * 256 + t];
        atomicAdd(&hist[d >> shift], 1);
    }
    __syncthreads();
    if (t < 128) base[t] = atomicAdd(&binA[g * 128 + t], hist[t]);
    __syncthreads();
    #pragma unroll
    for (int it = 0; it < 16; ++it) {
        const int e = e_base + it * 256 + t;
        const int s = src[e], d = dst[e];
        const int b = d >> shift;
        const int l = atomicAdd(&cur[b], 1);
        pairs[(size_t)g * NEDGE + base[b] + l] = make_int2(s, d);
    }
}

__global__ __launch_bounds__(256)
void binsort3(const int2* __restrict__ pairs, const int* __restrict__ rp_all,
              int* __restrict__ sorted_all) {
    __shared__ int cur[1024];
    const int g = blockIdx.x >> 7;
    const int b = blockIdx.x & 127;
    const int t = threadIdx.x;
    const int shift = shift_of(g);
    const int W = 1 << shift;
    const int d0 = b << shift;
    const int rpo = rp_off_of(g);
    for (int i = t; i < W; i += 256) cur[i] = rp_all[rpo + d0 + i];
    __syncthreads();
    const int e0 = rp_all[rpo + d0];
    const int e1 = rp_all[rpo + d0 + W];
    for (int e = e0 + t; e < e1; e += 256) {
        const int2 p = pairs[(size_t)g * NEDGE + e];
        const int pos = atomicAdd(&cur[p.y - d0], 1);
        sorted_all[(size_t)g * NEDGE + pos] = p.x;
    }
}

// ---------------- CSR aggregation (mean), bf16 features; 8/4/2-stride loops ----------------
__global__ __launch_bounds__(256)
void csr_gather_mean(const bf16_t* __restrict__ feat, const int* __restrict__ row_ptr,
                     const int* __restrict__ sorted_src, bf16_t* __restrict__ mean, int n) {
    const int lane = threadIdx.x & 63;
    const int half = lane >> 5;
    const int col8 = (lane & 31) * 8;
    const int w = blockIdx.x * 4 + (threadIdx.x >> 6);
    if (w >= n) return;
    const int e0 = row_ptr[w], e1 = row_ptr[w + 1];
    float acc[8] = {0.f, 0.f, 0.f, 0.f, 0.f, 0.f, 0.f, 0.f};
    int e = e0 + half;
    for (; e + 6 < e1; e += 8) {
        const int s0 = sorted_src[e],     s1 = sorted_src[e + 2];
        const int s2 = sorted_src[e + 4], s3 = sorted_src[e + 6];
        const bf16x8 v0 = *(const bf16x8*)(feat + (size_t)s0 * 256 + col8);
        const bf16x8 v1 = *(const bf16x8*)(feat + (size_t)s1 * 256 + col8);
        const bf16x8 v2 = *(const bf16x8*)(feat + (size_t)s2 * 256 + col8);
        const bf16x8 v3 = *(const bf16x8*)(feat + (size_t)s3 * 256 + col8);
        #pragma unroll
        for (int j = 0; j < 8; ++j)
            acc[j] += ((float)v0[j] + (float)v1[j]) + ((float)v2[j] + (float)v3[j]);
    }
    for (; e + 2 < e1; e += 4) {
        const int s0 = sorted_src[e], s1 = sorted_src[e + 2];
        const bf16x8 v0 = *(const bf16x8*)(feat + (size_t)s0 * 256 + col8);
        const bf16x8 v1 = *(const bf16x8*)(feat + (size_t)s1 * 256 + col8);
        #pragma unroll
        for (int j = 0; j < 8; ++j) acc[j] += (float)v0[j] + (float)v1[j];
    }
    for (; e < e1; e += 2) {
        const int s0 = sorted_src[e];
        const bf16x8 v0 = *(const bf16x8*)(feat + (size_t)s0 * 256 + col8);
        #pragma unroll
        for (int j = 0; j < 8; ++j) acc[j] += (float)v0[j];
    }
    #pragma unroll
    for (int j = 0; j < 8; ++j) acc[j] += __shfl_xor(acc[j], 32, 64);
    if (half == 0) {
        const float ic = 1.0f / fmaxf((float)(e1 - e0), 1.0f);
        bf16x8 r;
        #pragma unroll
        for (int j = 0; j < 8; ++j) r[j] = (bf16_t)(acc[j] * ic);
        *(bf16x8*)(mean + (size_t)w * 256 + col8) = r;
    }
}

// ---------------- merged cvt + small-K encoders ----------------
// blocks [0,2064): weight cvt; [2064,2576): K3/NHID; [2576,4624): K8/NDATA
__global__ __launch_bounds__(256)
void enc_cvt_both(WPtrs wp, bf16_t* __restrict__ wout,
                  const float* __restrict__ hx, const float* __restrict__ w3,
                  const float* __restrict__ b3, bf16_t* __restrict__ out3,
                  const float* __restrict__ dx, const float* __restrict__ w8,
                  const float* __restrict__ b8, bf16_t* __restrict__ out8) {
    __shared__ float ws[8 * 256];
    __shared__ float bs[256];
    const int t = threadIdx.x;
    if (blockIdx.x < 2064) {
        const int i = blockIdx.x * 256 + t;
        if (i < 8 * 65536) {
            const int wsel = i >> 16, off = i & 65535;
            wout[i] = (bf16_t)wp.p[wsel][off];
        } else if (i < 8 * 65536 + 2048) {
            wout[i] = (bf16_t)wp.p[8][i - 8 * 65536];
        } else {
            wout[i] = (bf16_t)wp.p[9][i - (8 * 65536 + 2048)];
        }
        return;
    }
    const int bid = blockIdx.x - 2064;
    const bool is8 = (bid >= 512);
    if (is8) {
        #pragma unroll
        for (int j = 0; j < 8; ++j) ws[j * 256 + t] = w8[t * 8 + j];
        bs[t] = b8[t];
    } else {
        #pragma unroll
        for (int j = 0; j < 3; ++j) ws[j * 256 + t] = w3[t * 3 + j];
        bs[t] = b3[t];
    }
    __syncthreads();
    const int lane = t & 63, wv = t >> 6;
    const int f0 = lane * 4;
    const float4 b4 = *(const float4*)(&bs[f0]);
    if (!is8) {
        for (int node = bid * 4 + wv; node < NHID; node += 512 * 4) {
            const float* xr = hx + (size_t)node * 3;
            float xv[3];
            #pragma unroll
            for (int j = 0; j < 3; ++j) xv[j] = xr[j];
            float a0 = b4.x, a1 = b4.y, a2 = b4.z, a3 = b4.w;
            #pragma unroll
            for (int j = 0; j < 3; ++j) {
                const float4 w4 = *(const float4*)(&ws[j * 256 + f0]);
                a0 += xv[j] * w4.x; a1 += xv[j] * w4.y;
                a2 += xv[j] * w4.z; a3 += xv[j] * w4.w;
            }
            bf16x4 r;
            r[0] = (bf16_t)gelu_f(a0); r[1] = (bf16_t)gelu_f(a1);
            r[2] = (bf16_t)gelu_f(a2); r[3] = (bf16_t)gelu_f(a3);
            *(bf16x4*)(out3 + (size_t)node * 256 + f0) = r;
        }
    } else {
        for (int node = (bid - 512) * 4 + wv; node < NDATA; node += 2048 * 4) {
            const float* xr = dx + (size_t)node * 8;
            float xv[8];
            #pragma unroll
            for (int j = 0; j < 8; ++j) xv[j] = xr[j];
            float a0 = b4.x, a1 = b4.y, a2 = b4.z, a3 = b4.w;
            #pragma unroll
            for (int j = 0; j < 8; ++j) {
                const float4 w4 = *(const float4*)(&ws[j * 256 + f0]);
                a0 += xv[j] * w4.x; a1 += xv[j] * w4.y;
                a2 += xv[j] * w4.z; a3 += xv[j] * w4.w;
            }
            bf16x4 r;
            r[0] = (bf16_t)gelu_f(a0); r[1] = (bf16_t)gelu_f(a1);
            r[2] = (bf16_t)gelu_f(a2); r[3] = (bf16_t)gelu_f(a3);
            *(bf16x4*)(out8 + (size_t)node * 256 + f0) = r;
        }
    }
}

// ---------------- MFMA bf16 GEMM — 64x128 tile ----------------
template<int DUAL, int ACT>
__global__ __launch_bounds__(256)
void mfma_gemm(const bf16_t* __restrict__ A1, const bf16_t* __restrict__ W1,
               const bf16_t* __restrict__ A2, const bf16_t* __restrict__ W2,
               const float* __restrict__ bias, bf16_t* __restrict__ C) {
    __shared__ bf16_t As[4 * 64 * 8];    // 4 KB
    __shared__ bf16_t Bs[4 * 128 * 8];   // 8 KB
    const int t = threadIdx.x;
    const int w = t >> 6, lane = t & 63;
    const int l15 = lane & 15, l4 = lane >> 4;
    const int m0 = (blockIdx.x >> 1) * 64;
    const int n0 = (blockIdx.x & 1) * 128;

    f32x4 acc[4][2];
    #pragma unroll
    for (int nb = 0; nb < 2; ++nb) {
        const float bv = bias ? bias[n0 + w * 32 + nb * 16 + l15] : 0.0f;
        #pragma unroll
        for (int m = 0; m < 4; ++m) {
            acc[m][nb][0] = bv; acc[m][nb][1] = bv; acc[m][nb][2] = bv; acc[m][nb][3] = bv;
        }
    }

    #pragma unroll
    for (int p = 0; p <= DUAL; ++p) {
        const bf16_t* Ap = p ? A2 : A1;
        const bf16_t* Wp = p ? W2 : W1;
        for (int kt = 0; kt < 8; ++kt) {
            const int k0 = kt * 32;
            __syncthreads();
            glds16(Ap + (size_t)(m0 + lane) * 256 + k0 + w * 8, &As[(w * 64) * 8]);
            glds16(Wp + (size_t)(n0 + lane) * 256 + k0 + w * 8, &Bs[(w * 128) * 8]);
            glds16(Wp + (size_t)(n0 + 64 + lane) * 256 + k0 + w * 8, &Bs[(w * 128 + 64) * 8]);
            __syncthreads();
            bf16x8 af[4], bfr[2];
            #pragma unroll
            for (int m = 0; m < 4; ++m)
                af[m] = *(const bf16x8*)(&As[(l4 * 64 + m * 16 + l15) * 8]);
            #pragma unroll
            for (int nb = 0; nb < 2; ++nb)
                bfr[nb] = *(const bf16x8*)(&Bs[(l4 * 128 + w * 32 + nb * 16 + l15) * 8]);
            #pragma unroll
            for (int m = 0; m < 4; ++m)
                #pragma unroll
                for (int nb = 0; nb < 2; ++nb)
                    acc[m][nb] = __builtin_amdgcn_mfma_f32_16x16x32_bf16(af[m], bfr[nb], acc[m][nb], 0, 0, 0);
        }
    }

    #pragma unroll
    for (int m = 0; m < 4; ++m) {
        #pragma unroll
        for (int nb = 0; nb < 2; ++nb) {
            const int col = n0 + w * 32 + nb * 16 + l15;
            #pragma unroll
            for (int i = 0; i < 4; ++i) {
                const int row = m0 + m * 16 + l4 * 4 + i;
                const float v = acc[m][nb][i];
                C[(size_t)row * 256 + col] = (bf16_t)(ACT ? gelu_f(v) : v);
            }
        }
    }
}

// ---------------- chained dual GEMM: C = (gelu(b1 + A1@W1^T)) @ W2^T ----------------
__global__ __launch_bounds__(256)
void gemm_chain2(const bf16_t* __restrict__ A1, const bf16_t* __restrict__ W1,
                 const float* __restrict__ b1, const bf16_t* __restrict__ W2,
                 bf16_t* __restrict__ C) {
    __shared__ bf16_t As[4 * 64 * 8];     // 4 KB
    __shared__ bf16_t Bs[4 * 256 * 8];    // 16 KB
    __shared__ bf16_t sL[32 * 64 * 8];    // 32 KB
    const int t = threadIdx.x;
    const int w = t >> 6, lane = t & 63;
    const int l15 = lane & 15, l4 = lane >> 4;
    const int m0 = blockIdx.x * 64;

    f32x4 acc[4][4];
    #pragma unroll
    for (int nb = 0; nb < 4; ++nb) {
        const float bv = b1[w * 64 + nb * 16 + l15];
        #pragma unroll
        for (int m = 0; m < 4; ++m) {
            acc[m][nb][0] = bv; acc[m][nb][1] = bv; acc[m][nb][2] = bv; acc[m][nb][3] = bv;
        }
    }

    for (int kt = 0; kt < 8; ++kt) {
        const int k0 = kt * 32;
        __syncthreads();
        glds16(A1 + (size_t)(m0 + lane) * 256 + k0 + w * 8, &As[(w * 64) * 8]);
        #pragma unroll
        for (int q = 0; q < 4; ++q)
            glds16(W1 + (size_t)(w * 64 + lane) * 256 + k0 + q * 8,
                   &Bs[(q * 256 + w * 64) * 8]);
        __syncthreads();
        bf16x8 af[4], bfr[4];
        #pragma unroll
        for (int m = 0; m < 4; ++m)
            af[m] = *(const bf16x8*)(&As[(l4 * 64 + m * 16 + l15) * 8]);
        #pragma unroll
        for (int nb = 0; nb < 4; ++nb)
            bfr[nb] = *(const bf16x8*)(&Bs[(l4 * 256 + w * 64 + nb * 16 + l15) * 8]);
        #pragma unroll
        for (int m = 0; m < 4; ++m)
            #pragma unroll
            for (int nb = 0; nb < 4; ++nb)
                acc[m][nb] = __builtin_amdgcn_mfma_f32_16x16x32_bf16(af[m], bfr[nb], acc[m][nb], 0, 0, 0);
    }
    #pragma unroll
    for (int m = 0; m < 4; ++m) {
        #pragma unroll
        for (int nb = 0; nb < 4; ++nb) {
            const int col = w * 64 + nb * 16 + l15;
            const int kq = col >> 3, cj = col & 7;
            #pragma unroll
            for (int i = 0; i < 4; ++i) {
                const int row = m * 16 + l4 * 4 + i;
                sL[(kq * 64 + row) * 8 + cj] = (bf16_t)gelu_f(acc[m][nb][i]);
            }
            acc[m][nb][0] = 0.f; acc[m][nb][1] = 0.f; acc[m][nb][2] = 0.f; acc[m][nb][3] = 0.f;
        }
    }
    __syncthreads();

    for (int kt = 0; kt < 8; ++kt) {
        const int k0 = kt * 32;
        __syncthreads();
        #pragma unroll
        for (int q = 0; q < 4; ++q)
            glds16(W2 + (size_t)(w * 64 + lane) * 256 + k0 + q * 8,
                   &Bs[(q * 256 + w * 64) * 8]);
        __syncthreads();
        bf16x8 af[4], bfr[4];
        #pragma unroll
        for (int m = 0; m < 4; ++m)
            af[m] = *(const bf16x8*)(&sL[((kt * 4 + l4) * 64 + m * 16 + l15) * 8]);
        #pragma unroll
        for (int nb = 0; nb < 4; ++nb)
            bfr[nb] = *(const bf16x8*)(&Bs[(l4 * 256 + w * 64 + nb * 16 + l15) * 8]);
        #pragma unroll
        for (int m = 0; m < 4; ++m)
            #pragma unroll
            for (int nb = 0; nb < 4; ++nb)
                acc[m][nb] = __builtin_amdgcn_mfma_f32_16x16x32_bf16(af[m], bfr[nb], acc[m][nb], 0, 0, 0);
    }

    #pragma unroll
    for (int m = 0; m < 4; ++m) {
        #pragma unroll
        for (int nb = 0; nb < 4; ++nb) {
            const int col = w * 64 + nb * 16 + l15;
            #pragma unroll
            for (int i = 0; i < 4; ++i) {
                const int row = m0 + m * 16 + l4 * 4 + i;
                C[(size_t)row * 256 + col] = (bf16_t)acc[m][nb][i];
            }
        }
    }
}

// ---------------- decoder (round-17 optimum): t = gelu(dec_bl + mean(sW) + d@W2^T) ----------------
// mean-add via identity-MFMA; d = gelu(x@Wd^T + bd) via K=8 MFMA staged per K-step (barriered).
__global__ __launch_bounds__(256)
void dec_gemm_m(const bf16_t* __restrict__ A1mean,
                const float* __restrict__ xdat, const float* __restrict__ Wd,
                const float* __restrict__ bd, const bf16_t* __restrict__ W2,
                const float* __restrict__ bias, const bf16_t* __restrict__ owb,
                const float* __restrict__ ob, float* __restrict__ out) {
    __shared__ __align__(16) char smem[25600];
    bf16_t* As   = (bf16_t*)smem;              // 4 KB  [4 kq][64 rows][8] (d tile)
    bf16_t* Bs   = (bf16_t*)(smem + 4096);     // 16 KB [4 kq][256 n][8]
    bf16_t* wd16 = (bf16_t*)(smem + 20480);    // 4 KB  Wd bf16 [256][8]
    float*  bdS  = (float*)(smem + 24576);     // 1 KB
    // epilogue overlays:
    bf16_t* tt   = (bf16_t*)smem;              // 16 KB
    float*  part = (float*)(smem + 16384);     // 8 KB

    const int t = threadIdx.x;
    const int w = t >> 6, lane = t & 63;
    const int l15 = lane & 15, l4 = lane >> 4;
    const int m0 = blockIdx.x * 64;

    {   // stage Wd (bf16) + bd
        const float4 wa = *(const float4*)(Wd + t * 8);
        const float4 wb = *(const float4*)(Wd + t * 8 + 4);
        bf16x8 wv;
        wv[0] = (bf16_t)wa.x; wv[1] = (bf16_t)wa.y; wv[2] = (bf16_t)wa.z; wv[3] = (bf16_t)wa.w;
        wv[4] = (bf16_t)wb.x; wv[5] = (bf16_t)wb.y; wv[6] = (bf16_t)wb.z; wv[7] = (bf16_t)wb.w;
        *(bf16x8*)(&wd16[t * 8]) = wv;
        bdS[t] = bd[t];
    }
    // x A-fragment for the K=8 d-MFMA (lanes l4>0 hold zeros)
    bf16x8 af_x;
    #pragma unroll
    for (int j = 0; j < 8; ++j) af_x[j] = (bf16_t)0.0f;
    if (l4 == 0) {
        const float* xrp = xdat + (size_t)(m0 + w * 16 + l15) * 8;
        const float4 xa = *(const float4*)(xrp);
        const float4 xb = *(const float4*)(xrp + 4);
        af_x[0] = (bf16_t)xa.x; af_x[1] = (bf16_t)xa.y; af_x[2] = (bf16_t)xa.z; af_x[3] = (bf16_t)xa.w;
        af_x[4] = (bf16_t)xb.x; af_x[5] = (bf16_t)xb.y; af_x[6] = (bf16_t)xb.z; af_x[7] = (bf16_t)xb.w;
    }

    // acc init: bias, then mean(sW) added via identity-MFMA
    f32x4 acc[4][4];
    #pragma unroll
    for (int nb = 0; nb < 4; ++nb) {
        const float bv = bias[w * 64 + nb * 16 + l15];
        #pragma unroll
        for (int m = 0; m < 4; ++m) {
            acc[m][nb][0] = bv; acc[m][nb][1] = bv; acc[m][nb][2] = bv; acc[m][nb][3] = bv;
        }
    }
    {
        bf16x8 ifr[2];
        #pragma unroll
        for (int p = 0; p < 2; ++p)
            #pragma unroll
            for (int j = 0; j < 8; ++j)
                ifr[p][j] = (bf16_t)((l4 * 8 + j == p * 16 + l15) ? 1.0f : 0.0f);
        #pragma unroll
        for (int m = 0; m < 4; ++m) {
            #pragma unroll
            for (int c = 0; c < 2; ++c) {
                const bf16x8 am = *(const bf16x8*)(A1mean +
                    (size_t)(m0 + m * 16 + l15) * 256 + (2 * w + c) * 32 + l4 * 8);
                acc[m][c * 2 + 0] = __builtin_amdgcn_mfma_f32_16x16x32_bf16(am, ifr[0], acc[m][c * 2 + 0], 0, 0, 0);
                acc[m][c * 2 + 1] = __builtin_amdgcn_mfma_f32_16x16x32_bf16(am, ifr[1], acc[m][c * 2 + 1], 0, 0, 0);
            }
        }
    }
    __syncthreads();   // wd16/bdS ready

    // single pass: d tile staged cross-wave per K-step (barriered)
    for (int kt = 0; kt < 8; ++kt) {
        const int k0 = kt * 32;
        __syncthreads();
        #pragma unroll
        for (int nb2 = 0; nb2 < 2; ++nb2) {
            const int cl = nb2 * 16 + l15;
            const int col = k0 + cl;
            f32x4 ad;
            const float bv = bdS[col];
            ad[0] = bv; ad[1] = bv; ad[2] = bv; ad[3] = bv;
            bf16x8 bf_d;
            #pragma unroll
            for (int j = 0; j < 8; ++j) bf_d[j] = (bf16_t)0.0f;
            if (l4 == 0) bf_d = *(const bf16x8*)(&wd16[col * 8]);
            ad = __builtin_amdgcn_mfma_f32_16x16x32_bf16(af_x, bf_d, ad, 0, 0, 0);
            const int kq = cl >> 3, jj = cl & 7;
            #pragma unroll
            for (int i = 0; i < 4; ++i)
                As[(kq * 64 + w * 16 + l4 * 4 + i) * 8 + jj] = (bf16_t)gelu_f(ad[i]);
        }
        #pragma unroll
        for (int q = 0; q < 4; ++q)
            glds16(W2 + (size_t)(w * 64 + lane) * 256 + k0 + q * 8,
                   &Bs[(q * 256 + w * 64) * 8]);
        __syncthreads();
        bf16x8 af[4], bfr[4];
        #pragma unroll
        for (int m = 0; m < 4; ++m)
            af[m] = *(const bf16x8*)(&As[(l4 * 64 + m * 16 + l15) * 8]);
        #pragma unroll
        for (int nb = 0; nb < 4; ++nb)
            bfr[nb] = *(const bf16x8*)(&Bs[(l4 * 256 + w * 64 + nb * 16 + l15) * 8]);
        #pragma unroll
        for (int m = 0; m < 4; ++m)
            #pragma unroll
            for (int nb = 0; nb < 4; ++nb)
                acc[m][nb] = __builtin_amdgcn_mfma_f32_16x16x32_bf16(af[m], bfr[nb], acc[m][nb], 0, 0, 0);
    }

    __syncthreads();   // main-loop buffers dead before tt/part overlay

    bf16x8 owf[2];
    #pragma unroll
    for (int s = 0; s < 2; ++s) {
        #pragma unroll
        for (int j = 0; j < 8; ++j) owf[s][j] = (bf16_t)0.0f;
        if (l15 < 8)
            owf[s] = *(const bf16x8*)(owb + l15 * 256 + w * 64 + s * 32 + l4 * 8);
    }

    bf16_t* ttw = tt + w * 2048;   // private per-wave [8 kq][32 rows][8]
    #pragma unroll
    for (int h = 0; h < 2; ++h) {
        #pragma unroll
        for (int mm = 0; mm < 2; ++mm) {
            const int m = h * 2 + mm;
            #pragma unroll
            for (int nb = 0; nb < 4; ++nb) {
                const int col = nb * 16 + l15;
                const int kg = col >> 3, cj = col & 7;
                #pragma unroll
                for (int i = 0; i < 4; ++i) {
                    const int rl = mm * 16 + l4 * 4 + i;
                    ttw[(kg * 32 + rl) * 8 + cj] = (bf16_t)gelu_f(acc[m][nb][i]);
                }
            }
        }
        f32x4 accp[2];
        #pragma unroll
        for (int mb = 0; mb < 2; ++mb) {
            accp[mb][0] = 0.f; accp[mb][1] = 0.f; accp[mb][2] = 0.f; accp[mb][3] = 0.f;
            #pragma unroll
            for (int s = 0; s < 2; ++s) {
                const bf16x8 af = *(const bf16x8*)(&ttw[((s * 4 + l4) * 32 + mb * 16 + l15) * 8]);
                accp[mb] = __builtin_amdgcn_mfma_f32_16x16x32_bf16(af, owf[s], accp[mb], 0, 0, 0);
            }
        }
        __syncthreads();
        #pragma unroll
        for (int mb = 0; mb < 2; ++mb)
            #pragma unroll
            for (int i = 0; i < 4; ++i)
                part[(w * 32 + mb * 16 + l4 * 4 + i) * 16 + l15] = accp[mb][i];
        __syncthreads();
        {
            const int row = t >> 3, o = t & 7;
            const float v = part[(0 * 32 + row) * 16 + o] + part[(1 * 32 + row) * 16 + o]
                          + part[(2 * 32 + row) * 16 + o] + part[(3 * 32 + row) * 16 + o] + ob[o];
            out[(size_t)(m0 + h * 32 + row) * 8 + o] = v;
        }
    }
}

// ---------------- launch ----------------

extern "C" void kernel_launch(void* const* d_in, const int* in_sizes, int n_in,
                              void* d_out, int out_size, void* d_ws, size_t ws_size,
                              hipStream_t stream) {
    const float* data_x   = (const float*)d_in[0];
    const float* hidden_x = (const float*)d_in[1];
    const int* dh_src = (const int*)d_in[2];
    const int* dh_dst = (const int*)d_in[3];
    const int* hh_src = (const int*)d_in[4];
    const int* hh_dst = (const int*)d_in[5];
    const int* hd_src = (const int*)d_in[6];
    const int* hd_dst = (const int*)d_in[7];
    const float* enc_src_w = (const float*)d_in[8];
    const float* enc_src_b = (const float*)d_in[9];
    const float* enc_dst_w = (const float*)d_in[10];
    const float* enc_dst_b = (const float*)d_in[11];
    const float* enc_wl = (const float*)d_in[12];
    const float* enc_bl = (const float*)d_in[13];
    const float* enc_wr = (const float*)d_in[14];
    const float* proc_wl = (const float*)d_in[15];
    const float* proc_bl = (const float*)d_in[16];
    const float* proc_wr = (const float*)d_in[17];
    const float* proc_mlp_w = (const float*)d_in[18];
    const float* proc_mlp_b = (const float*)d_in[19];
    const float* dec_src_w = (const float*)d_in[20];
    const float* dec_src_b = (const float*)d_in[21];
    const float* dec_dst_w = (const float*)d_in[22];
    const float* dec_dst_b = (const float*)d_in[23];
    const float* dec_wl = (const float*)d_in[24];
    const float* dec_bl = (const float*)d_in[25];
    const float* dec_wr = (const float*)d_in[26];
    const float* out_w  = (const float*)d_in[27];
    const float* out_b  = (const float*)d_in[28];
    float* out = (float*)d_out;

    // ---- workspace ----
    bf16_t* h_a   = (bf16_t*)d_ws;                       // NHID*256
    bf16_t* h_b   = h_a + (size_t)NHID * 256;            // NHID*256
    bf16_t* h_c   = h_b + (size_t)NHID * 256;            // NHID*256
    bf16_t* h_msg = h_c + (size_t)NHID * 256;            // NDATA*256
    bf16_t* dmean = h_msg + (size_t)NDATA * 256;         // NDATA*256
    bf16_t* wbuf  = dmean + (size_t)NDATA * 256;         // 8*65536 + 4096
    int* cnt_all    = (int*)(wbuf + 8 * 65536 + 4096);   // 2*NHID+NDATA
    int* rp_all     = cnt_all + (2 * NHID + NDATA);      // 2*(NHID+1)+NDATA+1
    int* sorted_all = rp_all + (2 * NHID + NDATA + 3);   // 3*NEDGE
    int* blk_sums   = sorted_all + (size_t)3 * NEDGE;    // 192
    int* binA       = blk_sums + 192;                    // 384
    int2* pairs     = (int2*)(((uintptr_t)(binA + 384) + 15) & ~(uintptr_t)15);  // 3*NEDGE int2

    bf16_t* W_enc_wl  = wbuf + 0 * 65536;
    bf16_t* W_enc_wr  = wbuf + 1 * 65536;
    bf16_t* W_proc_wl = wbuf + 2 * 65536;
    bf16_t* W_proc_wr = wbuf + 3 * 65536;
    bf16_t* W_mlp     = wbuf + 4 * 65536;
    bf16_t* W_dec_src = wbuf + 5 * 65536;
    bf16_t* W_dec_wl  = wbuf + 6 * 65536;
    bf16_t* W_dec_wr  = wbuf + 7 * 65536;
    bf16_t* W_out     = wbuf + 8 * 65536;            // 8x256
    bf16_t* W_dd      = wbuf + 8 * 65536 + 2048;     // 256x8 (dec_dst_w bf16, unused spare)

    const int* rp_dh = rp_all;
    const int* rp_hh = rp_all + NHID + 1;
    const int* rp_hd = rp_all + 2 * NHID + 2;
    const int* so_dh = sorted_all;
    const int* so_hh = sorted_all + NEDGE;
    const int* so_hd = sorted_all + 2 * (size_t)NEDGE;

    WPtrs wp;
    wp.p[0] = enc_wl;  wp.p[1] = enc_wr;  wp.p[2] = proc_wl; wp.p[3] = proc_wr;
    wp.p[4] = proc_mlp_w; wp.p[5] = dec_src_w; wp.p[6] = dec_wl; wp.p[7] = dec_wr;
    wp.p[8] = out_w; wp.p[9] = dec_dst_w;

    // ---- batched CSR build ----
    EdgePtrs ep;
    ep.src[0] = dh_src; ep.dst[0] = dh_dst;
    ep.src[1] = hh_src; ep.dst[1] = hh_dst;
    ep.src[2] = hd_src; ep.dst[2] = hd_dst;
    hipMemsetAsync(cnt_all, 0, (size_t)(2 * NHID + NDATA) * sizeof(int), stream);
    hist3<<<3 * 2048, 256, 0, stream>>>(ep, cnt_all);
    scan_blk3<<<192, 256, 0, stream>>>(cnt_all, rp_all, blk_sums);
    scan_add3<<<192, 256, 0, stream>>>(rp_all, blk_sums, rp_all, binA);
    partition3<<<3 * 128, 256, 0, stream>>>(ep, binA, pairs);
    binsort3<<<3 * 128, 256, 0, stream>>>(pairs, rp_all, sorted_all);

    // ---- cvt + encoders (merged) ----
    enc_cvt_both<<<4624, 256, 0, stream>>>(wp, wbuf,
                                           hidden_x, enc_dst_w, enc_dst_b, h_a,
                                           data_x, enc_src_w, enc_src_b, h_msg);
    csr_gather_mean<<<NHID / 4, 256, 0, stream>>>(h_msg, rp_dh, so_dh, h_b, NHID);
    // H1 = gelu(mean1@enc_wl^T + enc_bl + h_a@enc_wr^T) -> h_c
    mfma_gemm<1, 1><<<(NHID / 64) * 2, 256, 0, stream>>>(h_b, W_enc_wl, h_a, W_enc_wr, enc_bl, h_c);

    // ---- processor ----
    csr_gather_mean<<<NHID / 4, 256, 0, stream>>>(h_c, rp_hh, so_hh, h_a, NHID);
    // gelu(H2) -> h_b
    mfma_gemm<1, 1><<<(NHID / 64) * 2, 256, 0, stream>>>(h_a, W_proc_wl, h_c, W_proc_wr, proc_bl, h_b);
    // H3 -> h_a
    mfma_gemm<0, 1><<<(NHID / 64) * 2, 256, 0, stream>>>(h_b, W_mlp, nullptr, nullptr, proc_mlp_b, h_a);
    // chained: sW = gelu(H3@dec_src^T + b) @ dec_wl^T -> h_c
    gemm_chain2<<<NHID / 64, 256, 0, stream>>>(h_a, W_dec_src, dec_src_b, W_dec_wl, h_c);

    // ---- decoder: gather mean(sW), then fused final kernel (round-17 optimum) ----
    csr_gather_mean<<<NDATA / 4, 256, 0, stream>>>(h_c, rp_hd, so_hd, dmean, NDATA);
    dec_gemm_m<<<NDATA / 64, 256, 0, stream>>>(dmean, data_x, dec_dst_w, dec_dst_b,
                                               W_dec_wr, dec_bl, W_out, out_b, out);
}